// Round 1
// baseline (657.903 us; speedup 1.0000x reference)
//
#include <hip/hip_runtime.h>
#include <hip/hip_bf16.h>

typedef __hip_bfloat16 bf16;
typedef __attribute__((ext_vector_type(8))) short short8;
typedef __attribute__((ext_vector_type(4))) float f32x4;

struct bf16x8 { bf16 v[8]; };
struct bf16x4 { bf16 v[4]; };

__device__ __forceinline__ void gload_lds16(const void* g, void* l) {
  __builtin_amdgcn_global_load_lds(
      (const __attribute__((address_space(1))) void*)g,
      (__attribute__((address_space(3))) void*)l, 16, 0, 0);
}

__device__ __forceinline__ float wave_sum(float x) {
#pragma unroll
  for (int o = 32; o > 0; o >>= 1) x += __shfl_xor(x, o, 64);
  return x;
}

// ---------------- generic f32 -> bf16 cast (8 elems/thread) ----------------
__global__ void cast_bf16_k(const float* __restrict__ in, bf16* __restrict__ out, int n8) {
  int i = blockIdx.x * 256 + threadIdx.x;
  if (i >= n8) return;
  const float4* p = (const float4*)in + (size_t)i * 2;
  float4 a = p[0], b = p[1];
  bf16x8 o;
  o.v[0] = __float2bfloat16(a.x); o.v[1] = __float2bfloat16(a.y);
  o.v[2] = __float2bfloat16(a.z); o.v[3] = __float2bfloat16(a.w);
  o.v[4] = __float2bfloat16(b.x); o.v[5] = __float2bfloat16(b.y);
  o.v[6] = __float2bfloat16(b.z); o.v[7] = __float2bfloat16(b.w);
  ((bf16x8*)out)[i] = o;
}

__global__ void pack3_k(const float* __restrict__ a, const float* __restrict__ b,
                        const float* __restrict__ c, float* __restrict__ o) {
  int i = blockIdx.x * 256 + threadIdx.x;
  if (i >= 3072) return;
  const float* s = (i < 1024) ? a : (i < 2048) ? b : c;
  o[i] = s[i & 1023];
}

// ---------------- transpose-cast: XT[d][s] = x[s][d] (bf16) ----------------
__global__ void transpose_cast_k(const float* __restrict__ X, bf16* __restrict__ XT) {
  __shared__ float t[32][33];
  int bx = blockIdx.x, by = blockIdx.y;
  int tx = threadIdx.x & 31, ty = threadIdx.x >> 5;  // 32 x 8
#pragma unroll
  for (int r = ty; r < 32; r += 8)
    t[r][tx] = X[(size_t)(by * 32 + r) * 1024 + bx * 32 + tx];
  __syncthreads();
#pragma unroll
  for (int r = ty; r < 32; r += 8)
    XT[(size_t)(bx * 32 + r) * 1024 + by * 32 + tx] = __float2bfloat16(t[tx][r]);
}

// ---------------- T[k][l][s] = (s<=l) ? basis[l-s][k] : 0 ----------------
__global__ void build_T_k(const float* __restrict__ basis, bf16* __restrict__ T) {
  size_t i = (size_t)blockIdx.x * 256 + threadIdx.x;  // 16M
  int s = (int)(i & 1023);
  int l = (int)((i >> 10) & 1023);
  int k = (int)(i >> 20);
  float v = (s <= l) ? basis[(size_t)(l - s) * 16 + k] : 0.f;
  T[i] = __float2bfloat16(v);
}

// ---------------- MFMA GEMM, C = A @ B^T (+bias). 128x128 tile, BK=64 ------
// A: [M,K] bf16 row-major (lda), B: [N,K] bf16 row-major (ldb).
template<int TRI, int OUTBF, int HASB>
__global__ void gemm_bt(const bf16* __restrict__ A, long sAb, int lda,
                        const bf16* __restrict__ B, long sBb, int ldb,
                        void* __restrict__ Cv, long sCb, int ldc,
                        const float* __restrict__ bias, int sbias,
                        int M, int N, int K) {
  __shared__ bf16 As[128 * 64];
  __shared__ bf16 Bs[128 * 64];
  const int tid = threadIdx.x;
  const int lane = tid & 63;
  const int wid = tid >> 6;
  const int wr = wid >> 1, wc = wid & 1;
  const int bx = blockIdx.x, by = blockIdx.y, bz = blockIdx.z;
  const int r0 = by * 128, c0 = bx * 128;
  const bf16* Ab = A + (size_t)bz * sAb;
  const bf16* Bb = B + (size_t)bz * sBb;
  f32x4 acc[4][4] = {};
  const int kend = TRI ? min(K, r0 + 128) : K;
  for (int k0 = 0; k0 < kend; k0 += 64) {
    __syncthreads();
#pragma unroll
    for (int i = 0; i < 4; i++) {
      int idx = i * 256 + tid;
      int row = idx >> 3, cc = (idx & 7) << 3;
      gload_lds16(Ab + (size_t)(r0 + row) * lda + k0 + cc, &As[idx << 3]);
    }
#pragma unroll
    for (int i = 0; i < 4; i++) {
      int idx = i * 256 + tid;
      int row = idx >> 3, cc = (idx & 7) << 3;
      gload_lds16(Bb + (size_t)(c0 + row) * ldb + k0 + cc, &Bs[idx << 3]);
    }
    asm volatile("s_waitcnt vmcnt(0)" ::: "memory");
    __syncthreads();
#pragma unroll
    for (int ks = 0; ks < 2; ks++) {
      const int colo = ks * 32 + (lane >> 4) * 8;
      short8 af[4], bfr[4];
#pragma unroll
      for (int m = 0; m < 4; m++)
        af[m] = *(const short8*)&As[(wr * 64 + m * 16 + (lane & 15)) * 64 + colo];
#pragma unroll
      for (int n = 0; n < 4; n++)
        bfr[n] = *(const short8*)&Bs[(wc * 64 + n * 16 + (lane & 15)) * 64 + colo];
#pragma unroll
      for (int m = 0; m < 4; m++)
#pragma unroll
        for (int n = 0; n < 4; n++)
          acc[m][n] = __builtin_amdgcn_mfma_f32_16x16x32_bf16(af[m], bfr[n], acc[m][n], 0, 0, 0);
    }
  }
  const int rb = r0 + wr * 64 + ((lane >> 4) << 2);
  const int cb = c0 + wc * 64 + (lane & 15);
#pragma unroll
  for (int n = 0; n < 4; n++) {
    const int col = cb + n * 16;
    float bv = HASB ? bias[bz * sbias + col] : 0.f;
#pragma unroll
    for (int m = 0; m < 4; m++) {
#pragma unroll
      for (int j = 0; j < 4; j++) {
        const int row = rb + m * 16 + j;
        size_t off = (size_t)bz * sCb + (size_t)row * ldc + col;
        float v = acc[m][n][j] + bv;
        if (OUTBF) ((bf16*)Cv)[off] = __float2bfloat16(v);
        else       ((float*)Cv)[off] = v;
      }
    }
  }
}

// ---------------- split-K reduce + bias + cast ----------------
__global__ void reduce4_k(const float* __restrict__ p, const float* __restrict__ bias,
                          bf16* __restrict__ out) {
  int i = blockIdx.x * 256 + threadIdx.x;
  float v = p[i] + p[i + 1048576] + p[i + 2097152] + p[i + 3145728] + bias[i & 1023];
  out[i] = __float2bfloat16(v);
}

// ---------------- per-(h,l): l2norm k,v; sim; qsum; gate ----------------
__global__ void qkv_post_k(const float* __restrict__ qkv, const float* __restrict__ W,
                           const float* __restrict__ wgb, const float* __restrict__ scale,
                           float* __restrict__ qh, float* __restrict__ kn, float* __restrict__ vn,
                           float* __restrict__ sim, float* __restrict__ gz, float* __restrict__ qs) {
  __shared__ float Wl[64][65];
  int tid = threadIdx.x;
#pragma unroll
  for (int i = 0; i < 16; i++) {
    int c = i * 256 + tid;
    Wl[c >> 6][c & 63] = W[c];
  }
  __syncthreads();
  int lane = tid & 63;
  int gw = blockIdx.x * 4 + (tid >> 6);
  int h = gw >> 10, l = gw & 1023;
  const float* base = qkv + (size_t)l * 1024 + h * 64 + lane;
  float q = base[0];
  float k = base[1048576];
  float v = base[2097152];
  float knv = k * (1.f / fmaxf(sqrtf(wave_sum(k * k)), 1e-12f));
  float vnv = v * (1.f / fmaxf(sqrtf(wave_sum(v * v)), 1e-12f));
  float simv = wave_sum(q * knv);
  float qsv = wave_sum(q);
  float inner = 0.f;
#pragma unroll 8
  for (int n = 0; n < 64; n++)
    inner += Wl[lane][n] * __shfl(knv, n, 64);
  float gl = wave_sum(vnv * inner) * scale[h] + wgb[0];
  float yy = gl > 0.f ? gl : 0.01f * gl;
  float gzz = yy * yy + 1e-5f;
  size_t o = ((size_t)h * 1024 + l) * 64 + lane;
  qh[o] = q; kn[o] = knv; vn[o] = vnv;
  if (lane == 0) {
    sim[h * 1024 + l] = simv; gz[h * 1024 + l] = gzz; qs[h * 1024 + l] = qsv;
  }
}

// ---------------- online-softmax scan + gate cumsum (1 wave/head) ----------
__global__ void scan_head_k(const float* __restrict__ sim, const float* __restrict__ gz,
                            const float* __restrict__ vn, float* __restrict__ wts,
                            float* __restrict__ lin, float* __restrict__ gcum) {
  int h = blockIdx.x, lane = threadIdx.x;
  size_t hb = (size_t)h * 1024;
  float m = -1e30f, nrm = 0.f, vc = 0.f, gc = 0.f;
  for (int l = 0; l < 1024; l++) {
    float s = sim[hb + l], g = gz[hb + l];
    float vv = vn[(hb + l) * 64 + lane];
    float mn = fmaxf(m, s);
    float eo = expf(m - mn);
    float en = expf(s - mn);
    nrm = nrm * eo + en;
    vc = vc * eo + en * vv;
    m = mn;
    gc += g;
    float inv = 1.f / (nrm + 1e-5f);
    lin[(hb + l) * 64 + lane] = vc * inv;
    if (lane == 0) { wts[hb + l] = en * inv; gcum[hb + l] = gc; }
  }
}

// ---------------- per-(h,chunk) outer-product partial state ----------------
__global__ void chunk_outer_k(const float* __restrict__ vn, const float* __restrict__ kn,
                              const float* __restrict__ gz, float* __restrict__ Mc) {
  __shared__ float vns[64][64], kns[64][64], gzs[64];
  int c = blockIdx.x, h = blockIdx.y, tid = threadIdx.x;
  size_t base = ((size_t)h * 1024 + c * 64) * 64;
#pragma unroll
  for (int i = 0; i < 16; i++) {
    int e = i * 256 + tid;
    vns[e >> 6][e & 63] = vn[base + e];
    kns[e >> 6][e & 63] = kn[base + e];
  }
  if (tid < 64) gzs[tid] = gz[h * 1024 + c * 64 + tid];
  __syncthreads();
  float acc[16] = {};
  for (int s = 0; s < 64; s++) {
    float g = gzs[s];
#pragma unroll
    for (int i = 0; i < 16; i++) {
      int pn = i * 256 + tid;
      acc[i] += (g * vns[s][pn >> 6]) * kns[s][pn & 63];
    }
  }
  size_t ob = (size_t)(h * 16 + c) * 4096;
#pragma unroll
  for (int i = 0; i < 16; i++) Mc[ob + i * 256 + tid] = acc[i];
}

// ---------------- exclusive prefix over chunks ----------------
__global__ void chunk_prefix_k(const float* __restrict__ Mc, float* __restrict__ Sb) {
  int idx = blockIdx.x * 256 + threadIdx.x;  // 16*4096
  int h = idx >> 12, pn = idx & 4095;
  float a = 0.f;
  for (int c = 0; c < 16; c++) {
    size_t o = (size_t)(h * 16 + c) * 4096 + pn;
    Sb[o] = a; a += Mc[o];
  }
}

// ---------------- per-(h,chunk) gated linear attn + blend ----------------
__launch_bounds__(256)
__global__ void chunk_attn_k(const float* __restrict__ qh, const float* __restrict__ vn,
                             const float* __restrict__ kn, const float* __restrict__ gz,
                             const float* __restrict__ gcum, const float* __restrict__ Sb,
                             const float* __restrict__ wts, const float* __restrict__ lin,
                             const float* __restrict__ qs, const float* __restrict__ scale,
                             float* __restrict__ Yc) {
  __shared__ float qls[64][65], vls[64][65], kls[64][65], P[64][33], gzs[64];
  int c = blockIdx.x, h = blockIdx.y, tid = threadIdx.x;
  size_t base = ((size_t)h * 1024 + c * 64) * 64;
#pragma unroll
  for (int i = 0; i < 16; i++) {
    int e = i * 256 + tid;
    int r = e >> 6, cc = e & 63;
    qls[r][cc] = qh[base + e];
    vls[r][cc] = vn[base + e];
    kls[r][cc] = kn[base + e];
  }
  if (tid < 64) gzs[tid] = gz[h * 1024 + c * 64 + tid];
  __syncthreads();
  const float* S = Sb + ((size_t)h * 16 + c) * 4096;
  const int t0 = (tid >> 4) * 4, n0 = (tid & 15) * 4;
  float y[4][4] = {};
  // inter-chunk: q @ S_before
  for (int p = 0; p < 64; p++) {
    float av[4];
#pragma unroll
    for (int i2 = 0; i2 < 4; i2++) av[i2] = qls[t0 + i2][p];
    float4 bv = *(const float4*)(S + p * 64 + n0);
#pragma unroll
    for (int i2 = 0; i2 < 4; i2++) {
      y[i2][0] += av[i2] * bv.x; y[i2][1] += av[i2] * bv.y;
      y[i2][2] += av[i2] * bv.z; y[i2][3] += av[i2] * bv.w;
    }
  }
  // intra-chunk, two 32-wide s slabs
  const int tg = tid >> 3;
  const int s2b = (tid & 7) * 4;
  for (int s0 = 0; s0 < 64; s0 += 32) {
    float pv[2][4] = {};
    for (int k2 = 0; k2 < 64; k2++) {
      float a0 = qls[tg * 2][k2], a1 = qls[tg * 2 + 1][k2];
#pragma unroll
      for (int j = 0; j < 4; j++) {
        float b = vls[s0 + s2b + j][k2];
        pv[0][j] += a0 * b;
        pv[1][j] += a1 * b;
      }
    }
#pragma unroll
    for (int ii = 0; ii < 2; ii++)
#pragma unroll
      for (int j = 0; j < 4; j++) {
        int t = tg * 2 + ii, ss = s0 + s2b + j;
        P[t][ss - s0] = (ss <= t) ? pv[ii][j] * gzs[ss] : 0.f;
      }
    __syncthreads();
    for (int ss = 0; ss < 32; ss++) {
      float pr[4], kv[4];
#pragma unroll
      for (int i2 = 0; i2 < 4; i2++) pr[i2] = P[t0 + i2][ss];
#pragma unroll
      for (int j = 0; j < 4; j++) kv[j] = kls[s0 + ss][n0 + j];
#pragma unroll
      for (int i2 = 0; i2 < 4; i2++)
#pragma unroll
        for (int j = 0; j < 4; j++) y[i2][j] += pr[i2] * kv[j];
    }
    __syncthreads();
  }
  float sc = scale[h];
#pragma unroll
  for (int i2 = 0; i2 < 4; i2++) {
    int l = c * 64 + t0 + i2;
    size_t il = (size_t)h * 1024 + l;
    float gcv = gcum[il], wv = wts[il], qv = qs[il];
    float den = 1.f / (gcv + 1e-5f);
#pragma unroll
    for (int j = 0; j < 4; j++) {
      float yb = sc * y[i2][j] * den;
      float yl = qv * lin[il * 64 + n0 + j];
      Yc[(size_t)l * 1024 + h * 64 + n0 + j] = yb + (yl - yb) * wv;
    }
  }
}

// ---------------- row l2norm over D=1024 + cast ----------------
__global__ void rownorm_cast_k(const float* __restrict__ Y, bf16* __restrict__ out) {
  __shared__ float red[4];
  int l = blockIdx.x, tid = threadIdx.x;
  float4 v = ((const float4*)(Y + (size_t)l * 1024))[tid];
  float ss = v.x * v.x + v.y * v.y + v.z * v.z + v.w * v.w;
  ss = wave_sum(ss);
  int wid = tid >> 6, lane = tid & 63;
  if (lane == 0) red[wid] = ss;
  __syncthreads();
  float tot = red[0] + red[1] + red[2] + red[3];
  float inv = 1.f / fmaxf(sqrtf(tot), 1e-12f);
  bf16x4 o;
  o.v[0] = __float2bfloat16(v.x * inv); o.v[1] = __float2bfloat16(v.y * inv);
  o.v[2] = __float2bfloat16(v.z * inv); o.v[3] = __float2bfloat16(v.w * inv);
  ((bf16x4*)(out + (size_t)l * 1024))[tid] = o;
}

// ======================================================================
extern "C" void kernel_launch(void* const* d_in, const int* in_sizes, int n_in,
                              void* d_out, int out_size, void* d_ws, size_t ws_size,
                              hipStream_t stream) {
  (void)in_sizes; (void)n_in; (void)out_size; (void)ws_size;
  const float* x     = (const float*)d_in[0];
  const float* basis = (const float*)d_in[1];
  const float* mphiW = (const float*)d_in[2];
  const float* mphiB = (const float*)d_in[3];
  const float* wqW = (const float*)d_in[4];  const float* wqB = (const float*)d_in[5];
  const float* wkW = (const float*)d_in[6];  const float* wkB = (const float*)d_in[7];
  const float* wvW = (const float*)d_in[8];  const float* wvB = (const float*)d_in[9];
  const float* woW = (const float*)d_in[10]; const float* woB = (const float*)d_in[11];
  const float* wgW = (const float*)d_in[12]; const float* wgB = (const float*)d_in[13];
  const float* kvs = (const float*)d_in[14];
  float* out = (float*)d_out;
  char* ws = (char*)d_ws;

  bf16*  pre     = (bf16*)(ws + 0x0000000UL);   // [1024][16384] bf16 (33.6M)
  bf16*  Tbuf    = (bf16*)(ws + 0x2000000UL);   // [16][1024][1024] bf16 (33.6M)
  float* part2   = (float*)(ws + 0x2000000UL);  // aliases Tbuf (dead after stage1)
  bf16*  mphi_bf = (bf16*)(ws + 0x4000000UL);   // [1024][16384] bf16
  float* qkvf    = (float*)(ws + 0x4000000UL);  // aliases mphi_bf (dead after stage2)
  bf16*  xt_b    = (bf16*)(ws + 0x6000000UL);   // XT [1024][1024] bf16
  bf16*  xtil_bf = (bf16*)(ws + 0x6200000UL);   // x_tilde bf16
  bf16*  wqkv_bf = (bf16*)(ws + 0x6400000UL);   // [3][1024][1024] bf16
  bf16*  wo_bf   = (bf16*)(ws + 0x6A00000UL);
  float* qkv_bias= (float*)(ws + 0x6C00000UL);
  float* qh      = (float*)(ws + 0x6C10000UL);  // [16][1024][64] f32
  float* kn      = (float*)(ws + 0x7010000UL);
  float* vn      = (float*)(ws + 0x7410000UL);
  float* lin     = (float*)(ws + 0x7810000UL);
  float* Mc      = (float*)(ws + 0x7C10000UL);  // [16][16][4096]
  float* Sb      = (float*)(ws + 0x8010000UL);
  float* Yc      = (float*)(ws + 0x8410000UL);  // [1024][1024] f32
  bf16*  ynorm   = (bf16*)(ws + 0x8810000UL);
  float* simb    = (float*)(ws + 0x8A10000UL);
  float* gzb     = (float*)(ws + 0x8A20000UL);
  float* qsb     = (float*)(ws + 0x8A30000UL);
  float* wtb     = (float*)(ws + 0x8A40000UL);
  float* gcb     = (float*)(ws + 0x8A50000UL);

  // weight casts
  cast_bf16_k<<<8192, 256, 0, stream>>>(mphiW, mphi_bf, 2097152);
  cast_bf16_k<<<512, 256, 0, stream>>>(wqW, wqkv_bf, 131072);
  cast_bf16_k<<<512, 256, 0, stream>>>(wkW, wqkv_bf + 1048576, 131072);
  cast_bf16_k<<<512, 256, 0, stream>>>(wvW, wqkv_bf + 2097152, 131072);
  cast_bf16_k<<<512, 256, 0, stream>>>(woW, wo_bf, 131072);
  pack3_k<<<12, 256, 0, stream>>>(wqB, wkB, wvB, qkv_bias);
  transpose_cast_k<<<dim3(32, 32), 256, 0, stream>>>(x, xt_b);
  build_T_k<<<65536, 256, 0, stream>>>(basis, Tbuf);

  // stage1: pre[l][k*1024+d] = sum_s T_k[l][s] * x[s][d]  (triangular, batched over k)
  gemm_bt<1, 1, 0><<<dim3(8, 8, 16), 256, 0, stream>>>(
      Tbuf, 1048576L, 1024, xt_b, 0L, 1024, (void*)pre, 1024L, 16384,
      nullptr, 0, 1024, 1024, 1024);

  // stage2: x_tilde = pre @ M_phi_w^T (split-K x4)
  gemm_bt<0, 0, 0><<<dim3(8, 8, 4), 256, 0, stream>>>(
      pre, 4096L, 16384, mphi_bf, 4096L, 16384, (void*)part2, 1048576L, 1024,
      nullptr, 0, 1024, 1024, 4096);
  reduce4_k<<<4096, 256, 0, stream>>>(part2, mphiB, xtil_bf);

  // stage3: q,k,v
  gemm_bt<0, 0, 1><<<dim3(8, 8, 3), 256, 0, stream>>>(
      xtil_bf, 0L, 1024, wqkv_bf, 1048576L, 1024, (void*)qkvf, 1048576L, 1024,
      qkv_bias, 1024, 1024, 1024, 1024);

  // stage4: normalize k,v; sim; qsum; gates
  qkv_post_k<<<4096, 256, 0, stream>>>(qkvf, wgW, wgB, kvs, qh, kn, vn, simb, gzb, qsb);

  // stage5: online-softmax scan + gate cumsum
  scan_head_k<<<16, 64, 0, stream>>>(simb, gzb, vn, wtb, lin, gcb);

  // stage6: chunked gated linear attention + blend
  chunk_outer_k<<<dim3(16, 16), 256, 0, stream>>>(vn, kn, gzb, Mc);
  chunk_prefix_k<<<256, 256, 0, stream>>>(Mc, Sb);
  chunk_attn_k<<<dim3(16, 16), 256, 0, stream>>>(qh, vn, kn, gzb, gcb, Sb, wtb, lin, qsb, kvs, Yc);

  // stage7: row l2norm + cast
  rownorm_cast_k<<<1024, 256, 0, stream>>>(Yc, ynorm);

  // stage8: out = Ynorm @ wo^T + b
  gemm_bt<0, 0, 1><<<dim3(8, 8, 1), 256, 0, stream>>>(
      ynorm, 0L, 1024, wo_bf, 0L, 1024, (void*)out, 0L, 1024,
      woB, 0, 1024, 1024, 1024);
}

// Round 2
// 357.310 us; speedup vs baseline: 1.8413x; 1.8413x over previous
//
#include <hip/hip_runtime.h>
#include <hip/hip_bf16.h>

typedef __hip_bfloat16 bf16;
typedef __attribute__((ext_vector_type(8))) short short8;
typedef __attribute__((ext_vector_type(4))) float f32x4;

struct bf16x8 { bf16 v[8]; };
struct bf16x4 { bf16 v[4]; };

__device__ __forceinline__ void gload_lds16(const void* g, void* l) {
  __builtin_amdgcn_global_load_lds(
      (const __attribute__((address_space(1))) void*)g,
      (__attribute__((address_space(3))) void*)l, 16, 0, 0);
}

__device__ __forceinline__ float wave_sum(float x) {
#pragma unroll
  for (int o = 32; o > 0; o >>= 1) x += __shfl_xor(x, o, 64);
  return x;
}

// ---------------- generic f32 -> bf16 cast (8 elems/thread) ----------------
__global__ void cast_bf16_k(const float* __restrict__ in, bf16* __restrict__ out, int n8) {
  int i = blockIdx.x * 256 + threadIdx.x;
  if (i >= n8) return;
  const float4* p = (const float4*)in + (size_t)i * 2;
  float4 a = p[0], b = p[1];
  bf16x8 o;
  o.v[0] = __float2bfloat16(a.x); o.v[1] = __float2bfloat16(a.y);
  o.v[2] = __float2bfloat16(a.z); o.v[3] = __float2bfloat16(a.w);
  o.v[4] = __float2bfloat16(b.x); o.v[5] = __float2bfloat16(b.y);
  o.v[6] = __float2bfloat16(b.z); o.v[7] = __float2bfloat16(b.w);
  ((bf16x8*)out)[i] = o;
}

__global__ void pack3_k(const float* __restrict__ a, const float* __restrict__ b,
                        const float* __restrict__ c, float* __restrict__ o) {
  int i = blockIdx.x * 256 + threadIdx.x;
  if (i >= 3072) return;
  const float* s = (i < 1024) ? a : (i < 2048) ? b : c;
  o[i] = s[i & 1023];
}

// ---------------- transpose-cast: XT[d][s] = x[s][d] (bf16) ----------------
__global__ void transpose_cast_k(const float* __restrict__ X, bf16* __restrict__ XT) {
  __shared__ float t[32][33];
  int bx = blockIdx.x, by = blockIdx.y;
  int tx = threadIdx.x & 31, ty = threadIdx.x >> 5;  // 32 x 8
#pragma unroll
  for (int r = ty; r < 32; r += 8)
    t[r][tx] = X[(size_t)(by * 32 + r) * 1024 + bx * 32 + tx];
  __syncthreads();
#pragma unroll
  for (int r = ty; r < 32; r += 8)
    XT[(size_t)(bx * 32 + r) * 1024 + by * 32 + tx] = __float2bfloat16(t[tx][r]);
}

// ---------------- T[k][l][s] = (s<=l) ? basis[l-s][k] : 0 ----------------
__global__ void build_T_k(const float* __restrict__ basis, bf16* __restrict__ T) {
  size_t i = (size_t)blockIdx.x * 256 + threadIdx.x;  // 16M
  int s = (int)(i & 1023);
  int l = (int)((i >> 10) & 1023);
  int k = (int)(i >> 20);
  float v = (s <= l) ? basis[(size_t)(l - s) * 16 + k] : 0.f;
  T[i] = __float2bfloat16(v);
}

// ---------------- MFMA GEMM, C = A @ B^T (+bias). 128x128 tile, BK=64 ------
// A: [M,K] bf16 row-major (lda), B: [N,K] bf16 row-major (ldb).
template<int TRI, int OUTBF, int HASB>
__global__ void gemm_bt(const bf16* __restrict__ A, long sAb, int lda,
                        const bf16* __restrict__ B, long sBb, int ldb,
                        void* __restrict__ Cv, long sCb, int ldc,
                        const float* __restrict__ bias, int sbias,
                        int M, int N, int K) {
  __shared__ bf16 As[128 * 64];
  __shared__ bf16 Bs[128 * 64];
  const int tid = threadIdx.x;
  const int lane = tid & 63;
  const int wid = tid >> 6;
  const int wr = wid >> 1, wc = wid & 1;
  const int bx = blockIdx.x, by = blockIdx.y, bz = blockIdx.z;
  const int r0 = by * 128, c0 = bx * 128;
  const bf16* Ab = A + (size_t)bz * sAb;
  const bf16* Bb = B + (size_t)bz * sBb;
  f32x4 acc[4][4] = {};
  const int kend = TRI ? min(K, r0 + 128) : K;
  for (int k0 = 0; k0 < kend; k0 += 64) {
    __syncthreads();
#pragma unroll
    for (int i = 0; i < 4; i++) {
      int idx = i * 256 + tid;
      int row = idx >> 3, cc = (idx & 7) << 3;
      gload_lds16(Ab + (size_t)(r0 + row) * lda + k0 + cc, &As[idx << 3]);
    }
#pragma unroll
    for (int i = 0; i < 4; i++) {
      int idx = i * 256 + tid;
      int row = idx >> 3, cc = (idx & 7) << 3;
      gload_lds16(Bb + (size_t)(c0 + row) * ldb + k0 + cc, &Bs[idx << 3]);
    }
    asm volatile("s_waitcnt vmcnt(0)" ::: "memory");
    __syncthreads();
#pragma unroll
    for (int ks = 0; ks < 2; ks++) {
      const int colo = ks * 32 + (lane >> 4) * 8;
      short8 af[4], bfr[4];
#pragma unroll
      for (int m = 0; m < 4; m++)
        af[m] = *(const short8*)&As[(wr * 64 + m * 16 + (lane & 15)) * 64 + colo];
#pragma unroll
      for (int n = 0; n < 4; n++)
        bfr[n] = *(const short8*)&Bs[(wc * 64 + n * 16 + (lane & 15)) * 64 + colo];
#pragma unroll
      for (int m = 0; m < 4; m++)
#pragma unroll
        for (int n = 0; n < 4; n++)
          acc[m][n] = __builtin_amdgcn_mfma_f32_16x16x32_bf16(af[m], bfr[n], acc[m][n], 0, 0, 0);
    }
  }
  const int rb = r0 + wr * 64 + ((lane >> 4) << 2);
  const int cb = c0 + wc * 64 + (lane & 15);
#pragma unroll
  for (int n = 0; n < 4; n++) {
    const int col = cb + n * 16;
    float bv = HASB ? bias[bz * sbias + col] : 0.f;
#pragma unroll
    for (int m = 0; m < 4; m++) {
#pragma unroll
      for (int j = 0; j < 4; j++) {
        const int row = rb + m * 16 + j;
        size_t off = (size_t)bz * sCb + (size_t)row * ldc + col;
        float v = acc[m][n][j] + bv;
        if (OUTBF) ((bf16*)Cv)[off] = __float2bfloat16(v);
        else       ((float*)Cv)[off] = v;
      }
    }
  }
}

// ---------------- split-K reduce + bias + cast ----------------
__global__ void reduce4_k(const float* __restrict__ p, const float* __restrict__ bias,
                          bf16* __restrict__ out) {
  int i = blockIdx.x * 256 + threadIdx.x;
  float v = p[i] + p[i + 1048576] + p[i + 2097152] + p[i + 3145728] + bias[i & 1023];
  out[i] = __float2bfloat16(v);
}

// ---------------- per-(h,l): l2norm k,v; sim; qsum; gate ----------------
__global__ void qkv_post_k(const float* __restrict__ qkv, const float* __restrict__ W,
                           const float* __restrict__ wgb, const float* __restrict__ scale,
                           float* __restrict__ qh, float* __restrict__ kn, float* __restrict__ vn,
                           float* __restrict__ sim, float* __restrict__ gz, float* __restrict__ qs) {
  __shared__ float Wl[64][65];
  int tid = threadIdx.x;
#pragma unroll
  for (int i = 0; i < 16; i++) {
    int c = i * 256 + tid;
    Wl[c >> 6][c & 63] = W[c];
  }
  __syncthreads();
  int lane = tid & 63;
  int gw = blockIdx.x * 4 + (tid >> 6);
  int h = gw >> 10, l = gw & 1023;
  const float* base = qkv + (size_t)l * 1024 + h * 64 + lane;
  float q = base[0];
  float k = base[1048576];
  float v = base[2097152];
  float knv = k * (1.f / fmaxf(sqrtf(wave_sum(k * k)), 1e-12f));
  float vnv = v * (1.f / fmaxf(sqrtf(wave_sum(v * v)), 1e-12f));
  float simv = wave_sum(q * knv);
  float qsv = wave_sum(q);
  float inner = 0.f;
#pragma unroll 8
  for (int n = 0; n < 64; n++)
    inner += Wl[lane][n] * __shfl(knv, n, 64);
  float gl = wave_sum(vnv * inner) * scale[h] + wgb[0];
  float yy = gl > 0.f ? gl : 0.01f * gl;
  float gzz = yy * yy + 1e-5f;
  size_t o = ((size_t)h * 1024 + l) * 64 + lane;
  qh[o] = q; kn[o] = knv; vn[o] = vnv;
  if (lane == 0) {
    sim[h * 1024 + l] = simv; gz[h * 1024 + l] = gzz; qs[h * 1024 + l] = qsv;
  }
}

// ---------------- parallel online-softmax scan: phase 1 (per-chunk local) --
// grid (16 chunks, 16 heads), 64 threads. Lane owns one v-component.
__global__ void scan_local_k(const float* __restrict__ sim, const float* __restrict__ gz,
                             const float* __restrict__ vn,
                             float* __restrict__ mloc, float* __restrict__ nloc,
                             float* __restrict__ vloc, float* __restrict__ gloc,
                             float* __restrict__ mA, float* __restrict__ nA,
                             float* __restrict__ vA, float* __restrict__ gA) {
  int c = blockIdx.x, h = blockIdx.y, lane = threadIdx.x;
  size_t hb = (size_t)h * 1024 + c * 64;
  float m = -1e30f, n = 0.f, v = 0.f, g = 0.f;
  for (int i = 0; i < 64; i++) {
    float s = sim[hb + i];
    float gg = gz[hb + i];
    float vv = vn[(hb + i) * 64 + lane];
    float mn = fmaxf(m, s);
    float eo = expf(m - mn);
    float en = expf(s - mn);
    n = n * eo + en;
    v = v * eo + en * vv;
    m = mn;
    g += gg;
    vloc[(hb + i) * 64 + lane] = v;
    if (lane == 0) { mloc[hb + i] = m; nloc[hb + i] = n; gloc[hb + i] = g; }
  }
  size_t ix = (size_t)h * 16 + c;
  vA[ix * 64 + lane] = v;
  if (lane == 0) { mA[ix] = m; nA[ix] = n; gA[ix] = g; }
}

// ---------------- phase 2: exclusive prefix over 16 chunk aggregates -------
__global__ void scan_combine_k(const float* __restrict__ mA, const float* __restrict__ nA,
                               const float* __restrict__ vA, const float* __restrict__ gA,
                               float* __restrict__ mP, float* __restrict__ nP,
                               float* __restrict__ vP, float* __restrict__ gP) {
  int h = blockIdx.x, lane = threadIdx.x;
  float m = -1e30f, n = 0.f, v = 0.f, g = 0.f;
  for (int c = 0; c < 16; c++) {
    size_t ix = (size_t)h * 16 + c;
    vP[ix * 64 + lane] = v;
    if (lane == 0) { mP[ix] = m; nP[ix] = n; gP[ix] = g; }
    float mb = mA[ix], nb = nA[ix], gb = gA[ix];
    float vb = vA[ix * 64 + lane];
    float mn = fmaxf(m, mb);
    float ea = expf(m - mn), eb = expf(mb - mn);
    n = n * ea + nb * eb;
    v = v * ea + vb * eb;
    m = mn; g += gb;
  }
}

// ---------------- phase 3: combine prefix + local -> lin, wts, gcum --------
__global__ void scan_apply_k(const float* __restrict__ mloc, const float* __restrict__ nloc,
                             const float* __restrict__ vloc, const float* __restrict__ gloc,
                             const float* __restrict__ mP, const float* __restrict__ nP,
                             const float* __restrict__ vP, const float* __restrict__ gP,
                             const float* __restrict__ sim,
                             float* __restrict__ lin, float* __restrict__ wts,
                             float* __restrict__ gcum) {
  int tid = threadIdx.x;
  int gw = blockIdx.x * 4 + (tid >> 6);  // h*1024 + l
  int lane = tid & 63;
  int l = gw & 1023, h = gw >> 10;
  size_t ix = (size_t)h * 16 + (l >> 6);
  float mp = mP[ix], np = nP[ix], gp = gP[ix];
  float ml = mloc[gw], nl = nloc[gw], gl = gloc[gw];
  float vp = vP[ix * 64 + lane];
  float vl = vloc[(size_t)gw * 64 + lane];
  float mf = fmaxf(mp, ml);
  float ep = expf(mp - mf), el = expf(ml - mf);
  float nf = np * ep + nl * el;
  float vf = vp * ep + vl * el;
  float inv = 1.f / (nf + 1e-5f);
  lin[(size_t)gw * 64 + lane] = vf * inv;
  if (lane == 0) {
    wts[gw] = expf(sim[gw] - mf) * inv;
    gcum[gw] = gp + gl;
  }
}

// ---------------- per-(h,chunk) outer-product partial state ----------------
__global__ void chunk_outer_k(const float* __restrict__ vn, const float* __restrict__ kn,
                              const float* __restrict__ gz, float* __restrict__ Mc) {
  __shared__ float vns[64][64], kns[64][64], gzs[64];
  int c = blockIdx.x, h = blockIdx.y, tid = threadIdx.x;
  size_t base = ((size_t)h * 1024 + c * 64) * 64;
#pragma unroll
  for (int i = 0; i < 16; i++) {
    int e = i * 256 + tid;
    vns[e >> 6][e & 63] = vn[base + e];
    kns[e >> 6][e & 63] = kn[base + e];
  }
  if (tid < 64) gzs[tid] = gz[h * 1024 + c * 64 + tid];
  __syncthreads();
  float acc[16] = {};
  for (int s = 0; s < 64; s++) {
    float g = gzs[s];
#pragma unroll
    for (int i = 0; i < 16; i++) {
      int pn = i * 256 + tid;
      acc[i] += (g * vns[s][pn >> 6]) * kns[s][pn & 63];
    }
  }
  size_t ob = (size_t)(h * 16 + c) * 4096;
#pragma unroll
  for (int i = 0; i < 16; i++) Mc[ob + i * 256 + tid] = acc[i];
}

// ---------------- exclusive prefix over chunks ----------------
__global__ void chunk_prefix_k(const float* __restrict__ Mc, float* __restrict__ Sb) {
  int idx = blockIdx.x * 256 + threadIdx.x;  // 16*4096
  int h = idx >> 12, pn = idx & 4095;
  float a = 0.f;
  for (int c = 0; c < 16; c++) {
    size_t o = (size_t)(h * 16 + c) * 4096 + pn;
    Sb[o] = a; a += Mc[o];
  }
}

// ---------------- per-(h,chunk) gated linear attn + blend ----------------
__launch_bounds__(256)
__global__ void chunk_attn_k(const float* __restrict__ qh, const float* __restrict__ vn,
                             const float* __restrict__ kn, const float* __restrict__ gz,
                             const float* __restrict__ gcum, const float* __restrict__ Sb,
                             const float* __restrict__ wts, const float* __restrict__ lin,
                             const float* __restrict__ qs, const float* __restrict__ scale,
                             float* __restrict__ Yc) {
  __shared__ float qls[64][65], vls[64][65], kls[64][65], P[64][33], gzs[64];
  int c = blockIdx.x, h = blockIdx.y, tid = threadIdx.x;
  size_t base = ((size_t)h * 1024 + c * 64) * 64;
#pragma unroll
  for (int i = 0; i < 16; i++) {
    int e = i * 256 + tid;
    int r = e >> 6, cc = e & 63;
    qls[r][cc] = qh[base + e];
    vls[r][cc] = vn[base + e];
    kls[r][cc] = kn[base + e];
  }
  if (tid < 64) gzs[tid] = gz[h * 1024 + c * 64 + tid];
  __syncthreads();
  const float* S = Sb + ((size_t)h * 16 + c) * 4096;
  const int t0 = (tid >> 4) * 4, n0 = (tid & 15) * 4;
  float y[4][4] = {};
  // inter-chunk: q @ S_before
  for (int p = 0; p < 64; p++) {
    float av[4];
#pragma unroll
    for (int i2 = 0; i2 < 4; i2++) av[i2] = qls[t0 + i2][p];
    float4 bv = *(const float4*)(S + p * 64 + n0);
#pragma unroll
    for (int i2 = 0; i2 < 4; i2++) {
      y[i2][0] += av[i2] * bv.x; y[i2][1] += av[i2] * bv.y;
      y[i2][2] += av[i2] * bv.z; y[i2][3] += av[i2] * bv.w;
    }
  }
  // intra-chunk, two 32-wide s slabs
  const int tg = tid >> 3;
  const int s2b = (tid & 7) * 4;
  for (int s0 = 0; s0 < 64; s0 += 32) {
    float pv[2][4] = {};
    for (int k2 = 0; k2 < 64; k2++) {
      float a0 = qls[tg * 2][k2], a1 = qls[tg * 2 + 1][k2];
#pragma unroll
      for (int j = 0; j < 4; j++) {
        float b = vls[s0 + s2b + j][k2];
        pv[0][j] += a0 * b;
        pv[1][j] += a1 * b;
      }
    }
#pragma unroll
    for (int ii = 0; ii < 2; ii++)
#pragma unroll
      for (int j = 0; j < 4; j++) {
        int t = tg * 2 + ii, ss = s0 + s2b + j;
        P[t][ss - s0] = (ss <= t) ? pv[ii][j] * gzs[ss] : 0.f;
      }
    __syncthreads();
    for (int ss = 0; ss < 32; ss++) {
      float pr[4], kv[4];
#pragma unroll
      for (int i2 = 0; i2 < 4; i2++) pr[i2] = P[t0 + i2][ss];
#pragma unroll
      for (int j = 0; j < 4; j++) kv[j] = kls[s0 + ss][n0 + j];
#pragma unroll
      for (int i2 = 0; i2 < 4; i2++)
#pragma unroll
        for (int j = 0; j < 4; j++) y[i2][j] += pr[i2] * kv[j];
    }
    __syncthreads();
  }
  float sc = scale[h];
#pragma unroll
  for (int i2 = 0; i2 < 4; i2++) {
    int l = c * 64 + t0 + i2;
    size_t il = (size_t)h * 1024 + l;
    float gcv = gcum[il], wv = wts[il], qv = qs[il];
    float den = 1.f / (gcv + 1e-5f);
#pragma unroll
    for (int j = 0; j < 4; j++) {
      float yb = sc * y[i2][j] * den;
      float yl = qv * lin[il * 64 + n0 + j];
      Yc[(size_t)l * 1024 + h * 64 + n0 + j] = yb + (yl - yb) * wv;
    }
  }
}

// ---------------- row l2norm over D=1024 + cast ----------------
__global__ void rownorm_cast_k(const float* __restrict__ Y, bf16* __restrict__ out) {
  __shared__ float red[4];
  int l = blockIdx.x, tid = threadIdx.x;
  float4 v = ((const float4*)(Y + (size_t)l * 1024))[tid];
  float ss = v.x * v.x + v.y * v.y + v.z * v.z + v.w * v.w;
  ss = wave_sum(ss);
  int wid = tid >> 6, lane = tid & 63;
  if (lane == 0) red[wid] = ss;
  __syncthreads();
  float tot = red[0] + red[1] + red[2] + red[3];
  float inv = 1.f / fmaxf(sqrtf(tot), 1e-12f);
  bf16x4 o;
  o.v[0] = __float2bfloat16(v.x * inv); o.v[1] = __float2bfloat16(v.y * inv);
  o.v[2] = __float2bfloat16(v.z * inv); o.v[3] = __float2bfloat16(v.w * inv);
  ((bf16x4*)(out + (size_t)l * 1024))[tid] = o;
}

// ======================================================================
extern "C" void kernel_launch(void* const* d_in, const int* in_sizes, int n_in,
                              void* d_out, int out_size, void* d_ws, size_t ws_size,
                              hipStream_t stream) {
  (void)in_sizes; (void)n_in; (void)out_size; (void)ws_size;
  const float* x     = (const float*)d_in[0];
  const float* basis = (const float*)d_in[1];
  const float* mphiW = (const float*)d_in[2];
  const float* mphiB = (const float*)d_in[3];
  const float* wqW = (const float*)d_in[4];  const float* wqB = (const float*)d_in[5];
  const float* wkW = (const float*)d_in[6];  const float* wkB = (const float*)d_in[7];
  const float* wvW = (const float*)d_in[8];  const float* wvB = (const float*)d_in[9];
  const float* woW = (const float*)d_in[10]; const float* woB = (const float*)d_in[11];
  const float* wgW = (const float*)d_in[12]; const float* wgB = (const float*)d_in[13];
  const float* kvs = (const float*)d_in[14];
  float* out = (float*)d_out;
  char* ws = (char*)d_ws;

  bf16*  pre     = (bf16*)(ws + 0x0000000UL);   // [1024][16384] bf16 (33.6M)
  bf16*  Tbuf    = (bf16*)(ws + 0x2000000UL);   // [16][1024][1024] bf16 (33.6M)
  float* part2   = (float*)(ws + 0x2000000UL);  // aliases Tbuf (dead after stage1)
  bf16*  mphi_bf = (bf16*)(ws + 0x4000000UL);   // [1024][16384] bf16
  float* qkvf    = (float*)(ws + 0x4000000UL);  // aliases mphi_bf (dead after stage2)
  bf16*  xt_b    = (bf16*)(ws + 0x6000000UL);   // XT [1024][1024] bf16
  bf16*  xtil_bf = (bf16*)(ws + 0x6200000UL);   // x_tilde bf16
  bf16*  wqkv_bf = (bf16*)(ws + 0x6400000UL);   // [3][1024][1024] bf16
  bf16*  wo_bf   = (bf16*)(ws + 0x6A00000UL);
  float* qkv_bias= (float*)(ws + 0x6C00000UL);
  float* qh      = (float*)(ws + 0x6C10000UL);  // [16][1024][64] f32
  float* kn      = (float*)(ws + 0x7010000UL);
  float* vn      = (float*)(ws + 0x7410000UL);
  float* lin     = (float*)(ws + 0x7810000UL);
  float* Mc      = (float*)(ws + 0x7C10000UL);  // [16][16][4096]
  float* Sb      = (float*)(ws + 0x8010000UL);
  float* Yc      = (float*)(ws + 0x8410000UL);  // [1024][1024] f32
  bf16*  ynorm   = (bf16*)(ws + 0x8810000UL);
  float* simb    = (float*)(ws + 0x8A10000UL);
  float* gzb     = (float*)(ws + 0x8A20000UL);
  float* qsb     = (float*)(ws + 0x8A30000UL);
  float* wtb     = (float*)(ws + 0x8A40000UL);
  float* gcb     = (float*)(ws + 0x8A50000UL);
  // scan scratch: lives in the dead part2/Tbuf region (0x2000000..0x4000000)
  float* vloc = (float*)(ws + 0x2000000UL);  // [16,1024,64] (4MB)
  float* mloc = (float*)(ws + 0x2400000UL);  // [16,1024]
  float* nloc = (float*)(ws + 0x2410000UL);
  float* gloc = (float*)(ws + 0x2420000UL);
  float* mA   = (float*)(ws + 0x2430000UL);  // [16,16]
  float* nA   = (float*)(ws + 0x2431000UL);
  float* gA   = (float*)(ws + 0x2432000UL);
  float* vA   = (float*)(ws + 0x2440000UL);  // [16,16,64]
  float* mP   = (float*)(ws + 0x2450000UL);
  float* nP   = (float*)(ws + 0x2451000UL);
  float* gP   = (float*)(ws + 0x2452000UL);
  float* vP   = (float*)(ws + 0x2460000UL);  // [16,16,64]

  // weight casts
  cast_bf16_k<<<8192, 256, 0, stream>>>(mphiW, mphi_bf, 2097152);
  cast_bf16_k<<<512, 256, 0, stream>>>(wqW, wqkv_bf, 131072);
  cast_bf16_k<<<512, 256, 0, stream>>>(wkW, wqkv_bf + 1048576, 131072);
  cast_bf16_k<<<512, 256, 0, stream>>>(wvW, wqkv_bf + 2097152, 131072);
  cast_bf16_k<<<512, 256, 0, stream>>>(woW, wo_bf, 131072);
  pack3_k<<<12, 256, 0, stream>>>(wqB, wkB, wvB, qkv_bias);
  transpose_cast_k<<<dim3(32, 32), 256, 0, stream>>>(x, xt_b);
  build_T_k<<<65536, 256, 0, stream>>>(basis, Tbuf);

  // stage1: pre[l][k*1024+d] = sum_s T_k[l][s] * x[s][d]  (triangular, batched over k)
  gemm_bt<1, 1, 0><<<dim3(8, 8, 16), 256, 0, stream>>>(
      Tbuf, 1048576L, 1024, xt_b, 0L, 1024, (void*)pre, 1024L, 16384,
      nullptr, 0, 1024, 1024, 1024);

  // stage2: x_tilde = pre @ M_phi_w^T (split-K x4)
  gemm_bt<0, 0, 0><<<dim3(8, 8, 4), 256, 0, stream>>>(
      pre, 4096L, 16384, mphi_bf, 4096L, 16384, (void*)part2, 1048576L, 1024,
      nullptr, 0, 1024, 1024, 4096);
  reduce4_k<<<4096, 256, 0, stream>>>(part2, mphiB, xtil_bf);

  // stage3: q,k,v
  gemm_bt<0, 0, 1><<<dim3(8, 8, 3), 256, 0, stream>>>(
      xtil_bf, 0L, 1024, wqkv_bf, 1048576L, 1024, (void*)qkvf, 1048576L, 1024,
      qkv_bias, 1024, 1024, 1024, 1024);

  // stage4: normalize k,v; sim; qsum; gates
  qkv_post_k<<<4096, 256, 0, stream>>>(qkvf, wgW, wgB, kvs, qh, kn, vn, simb, gzb, qsb);

  // stage5: parallel online-softmax scan + gate cumsum (3 phases)
  scan_local_k<<<dim3(16, 16), 64, 0, stream>>>(simb, gzb, vn, mloc, nloc, vloc, gloc,
                                                mA, nA, vA, gA);
  scan_combine_k<<<16, 64, 0, stream>>>(mA, nA, vA, gA, mP, nP, vP, gP);
  scan_apply_k<<<4096, 256, 0, stream>>>(mloc, nloc, vloc, gloc, mP, nP, vP, gP,
                                         simb, lin, wtb, gcb);

  // stage6: chunked gated linear attention + blend
  chunk_outer_k<<<dim3(16, 16), 256, 0, stream>>>(vn, kn, gzb, Mc);
  chunk_prefix_k<<<256, 256, 0, stream>>>(Mc, Sb);
  chunk_attn_k<<<dim3(16, 16), 256, 0, stream>>>(qh, vn, kn, gzb, gcb, Sb, wtb, lin, qsb, kvs, Yc);

  // stage7: row l2norm + cast
  rownorm_cast_k<<<1024, 256, 0, stream>>>(Yc, ynorm);

  // stage8: out = Ynorm @ wo^T + b
  gemm_bt<0, 0, 1><<<dim3(8, 8, 1), 256, 0, stream>>>(
      ynorm, 0L, 1024, wo_bf, 0L, 1024, (void*)out, 0L, 1024,
      woB, 0, 1024, 1024, 1024);
}

// Round 3
// 335.603 us; speedup vs baseline: 1.9604x; 1.0647x over previous
//
#include <hip/hip_runtime.h>
#include <hip/hip_bf16.h>

typedef __hip_bfloat16 bf16;
typedef __attribute__((ext_vector_type(8))) short short8;
typedef __attribute__((ext_vector_type(4))) float f32x4;

struct bf16x8 { bf16 v[8]; };
struct bf16x4 { bf16 v[4]; };

__device__ __forceinline__ void gload_lds16(const void* g, void* l) {
  __builtin_amdgcn_global_load_lds(
      (const __attribute__((address_space(1))) void*)g,
      (__attribute__((address_space(3))) void*)l, 16, 0, 0);
}

__device__ __forceinline__ float wave_sum(float x) {
#pragma unroll
  for (int o = 32; o > 0; o >>= 1) x += __shfl_xor(x, o, 64);
  return x;
}

// ---------------- generic f32 -> bf16 cast (8 elems/thread) ----------------
__global__ void cast_bf16_k(const float* __restrict__ in, bf16* __restrict__ out, int n8) {
  int i = blockIdx.x * 256 + threadIdx.x;
  if (i >= n8) return;
  const float4* p = (const float4*)in + (size_t)i * 2;
  float4 a = p[0], b = p[1];
  bf16x8 o;
  o.v[0] = __float2bfloat16(a.x); o.v[1] = __float2bfloat16(a.y);
  o.v[2] = __float2bfloat16(a.z); o.v[3] = __float2bfloat16(a.w);
  o.v[4] = __float2bfloat16(b.x); o.v[5] = __float2bfloat16(b.y);
  o.v[6] = __float2bfloat16(b.z); o.v[7] = __float2bfloat16(b.w);
  ((bf16x8*)out)[i] = o;
}

// ---- fused: cast wq/wk/wv/wo (1024x1024 each) + pack qkv bias -------------
__global__ void cast_small_k(const float* __restrict__ wq, const float* __restrict__ wk,
                             const float* __restrict__ wv, const float* __restrict__ wo,
                             const float* __restrict__ bq, const float* __restrict__ bk,
                             const float* __restrict__ bv,
                             bf16* __restrict__ wqkv, bf16* __restrict__ wo_bf,
                             float* __restrict__ qkv_bias) {
  int b = blockIdx.x, tid = threadIdx.x;
  if (b < 2048) {
    const float* src = (b < 512) ? wq : (b < 1024) ? wk : (b < 1536) ? wv : wo;
    bf16* dst = (b < 512) ? wqkv : (b < 1024) ? (wqkv + 1048576)
               : (b < 1536) ? (wqkv + 2097152) : wo_bf;
    int i = (b & 511) * 256 + tid;
    const float4* p = (const float4*)src + (size_t)i * 2;
    float4 a = p[0], c = p[1];
    bf16x8 o;
    o.v[0] = __float2bfloat16(a.x); o.v[1] = __float2bfloat16(a.y);
    o.v[2] = __float2bfloat16(a.z); o.v[3] = __float2bfloat16(a.w);
    o.v[4] = __float2bfloat16(c.x); o.v[5] = __float2bfloat16(c.y);
    o.v[6] = __float2bfloat16(c.z); o.v[7] = __float2bfloat16(c.w);
    ((bf16x8*)dst)[i] = o;
  } else {
    int i = (b - 2048) * 256 + tid;
    if (i < 3072) {
      const float* s = (i < 1024) ? bq : (i < 2048) ? bk : bv;
      qkv_bias[i] = s[i & 1023];
    }
  }
}

// ---------------- transpose-cast: XT[d][s] = x[s][d] (bf16) ----------------
__global__ void transpose_cast_k(const float* __restrict__ X, bf16* __restrict__ XT) {
  __shared__ float t[32][33];
  int bx = blockIdx.x, by = blockIdx.y;
  int tx = threadIdx.x & 31, ty = threadIdx.x >> 5;  // 32 x 8
#pragma unroll
  for (int r = ty; r < 32; r += 8)
    t[r][tx] = X[(size_t)(by * 32 + r) * 1024 + bx * 32 + tx];
  __syncthreads();
#pragma unroll
  for (int r = ty; r < 32; r += 8)
    XT[(size_t)(bx * 32 + r) * 1024 + by * 32 + tx] = __float2bfloat16(t[tx][r]);
}

// ---------------- T[k][l][s] = (s<=l) ? basis[l-s][k] : 0 ----------------
__global__ void build_T_k(const float* __restrict__ basis, bf16* __restrict__ T) {
  size_t i = (size_t)blockIdx.x * 256 + threadIdx.x;  // 16M
  int s = (int)(i & 1023);
  int l = (int)((i >> 10) & 1023);
  int k = (int)(i >> 20);
  float v = (s <= l) ? basis[(size_t)(l - s) * 16 + k] : 0.f;
  T[i] = __float2bfloat16(v);
}

// ---------------- MFMA GEMM, C = A @ B^T (+bias). 128x128 tile, BK=64 ------
// Double-buffered (T3-minimum): STAGE(t+1) issued before compute(t),
// counted vmcnt(8) keeps next-tile loads in flight across the barrier.
// A: [M,K] bf16 row-major (lda), B: [N,K] bf16 row-major (ldb).
template<int TRI, int OUTBF, int HASB>
__global__ void gemm_bt(const bf16* __restrict__ A, long sAb, int lda,
                        const bf16* __restrict__ B, long sBb, int ldb,
                        void* __restrict__ Cv, long sCb, int ldc,
                        const float* __restrict__ bias, int sbias,
                        int M, int N, int K) {
  __shared__ bf16 As[2][128 * 64];
  __shared__ bf16 Bs[2][128 * 64];
  const int tid = threadIdx.x;
  const int lane = tid & 63;
  const int wid = tid >> 6;
  const int wr = wid >> 1, wc = wid & 1;
  const int bx = blockIdx.x, by = blockIdx.y, bz = blockIdx.z;
  const int r0 = by * 128, c0 = bx * 128;
  const bf16* Ab = A + (size_t)bz * sAb;
  const bf16* Bb = B + (size_t)bz * sBb;
  f32x4 acc[4][4] = {};
  const int kend = TRI ? min(K, r0 + 128) : K;
  const int nt = kend >> 6;

  // per-thread staging coords (8 loads: 4 A + 4 B)
  const int srow = tid >> 3, scol = (tid & 7) << 3;

#define STAGE(buf, k0)                                                        \
  {                                                                           \
    _Pragma("unroll")                                                         \
    for (int i = 0; i < 4; i++) {                                             \
      int row = i * 32 + srow;                                                \
      gload_lds16(Ab + (size_t)(r0 + row) * lda + (k0) + scol,                \
                  &As[buf][(row << 6) + scol]);                               \
    }                                                                         \
    _Pragma("unroll")                                                         \
    for (int i = 0; i < 4; i++) {                                             \
      int row = i * 32 + srow;                                                \
      gload_lds16(Bb + (size_t)(c0 + row) * ldb + (k0) + scol,                \
                  &Bs[buf][(row << 6) + scol]);                               \
    }                                                                         \
  }

  STAGE(0, 0)
  int cur = 0;
  for (int t = 0; t < nt; ++t) {
    if (t + 1 < nt) {
      STAGE(cur ^ 1, (t + 1) << 6)
      asm volatile("s_waitcnt vmcnt(8)" ::: "memory");
    } else {
      asm volatile("s_waitcnt vmcnt(0)" ::: "memory");
    }
    __syncthreads();
#pragma unroll
    for (int ks = 0; ks < 2; ks++) {
      const int colo = ks * 32 + (lane >> 4) * 8;
      short8 af[4], bfr[4];
#pragma unroll
      for (int m = 0; m < 4; m++)
        af[m] = *(const short8*)&As[cur][(wr * 64 + m * 16 + (lane & 15)) * 64 + colo];
#pragma unroll
      for (int n = 0; n < 4; n++)
        bfr[n] = *(const short8*)&Bs[cur][(wc * 64 + n * 16 + (lane & 15)) * 64 + colo];
#pragma unroll
      for (int m = 0; m < 4; m++)
#pragma unroll
        for (int n = 0; n < 4; n++)
          acc[m][n] = __builtin_amdgcn_mfma_f32_16x16x32_bf16(af[m], bfr[n], acc[m][n], 0, 0, 0);
    }
    __syncthreads();
    cur ^= 1;
  }
#undef STAGE

  const int rb = r0 + wr * 64 + ((lane >> 4) << 2);
  const int cb = c0 + wc * 64 + (lane & 15);
#pragma unroll
  for (int n = 0; n < 4; n++) {
    const int col = cb + n * 16;
    float bv = HASB ? bias[bz * sbias + col] : 0.f;
#pragma unroll
    for (int m = 0; m < 4; m++) {
#pragma unroll
      for (int j = 0; j < 4; j++) {
        const int row = rb + m * 16 + j;
        size_t off = (size_t)bz * sCb + (size_t)row * ldc + col;
        float v = acc[m][n][j] + bv;
        if (OUTBF) ((bf16*)Cv)[off] = __float2bfloat16(v);
        else       ((float*)Cv)[off] = v;
      }
    }
  }
}

// ---------------- split-K x8 reduce + bias + cast ----------------
__global__ void reduce8_k(const float* __restrict__ p, const float* __restrict__ bias,
                          bf16* __restrict__ out) {
  int i = blockIdx.x * 256 + threadIdx.x;
  float v = bias[i & 1023];
#pragma unroll
  for (int j = 0; j < 8; j++) v += p[i + j * 1048576];
  out[i] = __float2bfloat16(v);
}

// ---------------- per-(h,l): l2norm k,v; sim; qsum; gate ----------------
__global__ void qkv_post_k(const float* __restrict__ qkv, const float* __restrict__ W,
                           const float* __restrict__ wgb, const float* __restrict__ scale,
                           float* __restrict__ qh, float* __restrict__ kn, float* __restrict__ vn,
                           float* __restrict__ sim, float* __restrict__ gz, float* __restrict__ qs) {
  __shared__ float Wl[64][65];
  int tid = threadIdx.x;
#pragma unroll
  for (int i = 0; i < 16; i++) {
    int c = i * 256 + tid;
    Wl[c >> 6][c & 63] = W[c];
  }
  __syncthreads();
  int lane = tid & 63;
  int gw = blockIdx.x * 4 + (tid >> 6);
  int h = gw >> 10, l = gw & 1023;
  const float* base = qkv + (size_t)l * 1024 + h * 64 + lane;
  float q = base[0];
  float k = base[1048576];
  float v = base[2097152];
  float knv = k * (1.f / fmaxf(sqrtf(wave_sum(k * k)), 1e-12f));
  float vnv = v * (1.f / fmaxf(sqrtf(wave_sum(v * v)), 1e-12f));
  float simv = wave_sum(q * knv);
  float qsv = wave_sum(q);
  float inner = 0.f;
#pragma unroll 8
  for (int n = 0; n < 64; n++)
    inner += Wl[lane][n] * __shfl(knv, n, 64);
  float gl = wave_sum(vnv * inner) * scale[h] + wgb[0];
  float yy = gl > 0.f ? gl : 0.01f * gl;
  float gzz = yy * yy + 1e-5f;
  size_t o = ((size_t)h * 1024 + l) * 64 + lane;
  qh[o] = q; kn[o] = knv; vn[o] = vnv;
  if (lane == 0) {
    sim[h * 1024 + l] = simv; gz[h * 1024 + l] = gzz; qs[h * 1024 + l] = qsv;
  }
}

// ---------------- parallel online-softmax scan: phase 1 (per-chunk local) --
__global__ void scan_local_k(const float* __restrict__ sim, const float* __restrict__ gz,
                             const float* __restrict__ vn,
                             float* __restrict__ mloc, float* __restrict__ nloc,
                             float* __restrict__ vloc, float* __restrict__ gloc,
                             float* __restrict__ mA, float* __restrict__ nA,
                             float* __restrict__ vA, float* __restrict__ gA) {
  int c = blockIdx.x, h = blockIdx.y, lane = threadIdx.x;
  size_t hb = (size_t)h * 1024 + c * 64;
  float m = -1e30f, n = 0.f, v = 0.f, g = 0.f;
  for (int i = 0; i < 64; i++) {
    float s = sim[hb + i];
    float gg = gz[hb + i];
    float vv = vn[(hb + i) * 64 + lane];
    float mn = fmaxf(m, s);
    float eo = expf(m - mn);
    float en = expf(s - mn);
    n = n * eo + en;
    v = v * eo + en * vv;
    m = mn;
    g += gg;
    vloc[(hb + i) * 64 + lane] = v;
    if (lane == 0) { mloc[hb + i] = m; nloc[hb + i] = n; gloc[hb + i] = g; }
  }
  size_t ix = (size_t)h * 16 + c;
  vA[ix * 64 + lane] = v;
  if (lane == 0) { mA[ix] = m; nA[ix] = n; gA[ix] = g; }
}

// ---------------- phase 2: exclusive prefix over 16 chunk aggregates -------
__global__ void scan_combine_k(const float* __restrict__ mA, const float* __restrict__ nA,
                               const float* __restrict__ vA, const float* __restrict__ gA,
                               float* __restrict__ mP, float* __restrict__ nP,
                               float* __restrict__ vP, float* __restrict__ gP) {
  int h = blockIdx.x, lane = threadIdx.x;
  float m = -1e30f, n = 0.f, v = 0.f, g = 0.f;
  for (int c = 0; c < 16; c++) {
    size_t ix = (size_t)h * 16 + c;
    vP[ix * 64 + lane] = v;
    if (lane == 0) { mP[ix] = m; nP[ix] = n; gP[ix] = g; }
    float mb = mA[ix], nb = nA[ix], gb = gA[ix];
    float vb = vA[ix * 64 + lane];
    float mn = fmaxf(m, mb);
    float ea = expf(m - mn), eb = expf(mb - mn);
    n = n * ea + nb * eb;
    v = v * ea + vb * eb;
    m = mn; g += gb;
  }
}

// ---------------- phase 3: combine prefix + local -> lin, wts, gcum --------
__global__ void scan_apply_k(const float* __restrict__ mloc, const float* __restrict__ nloc,
                             const float* __restrict__ vloc, const float* __restrict__ gloc,
                             const float* __restrict__ mP, const float* __restrict__ nP,
                             const float* __restrict__ vP, const float* __restrict__ gP,
                             const float* __restrict__ sim,
                             float* __restrict__ lin, float* __restrict__ wts,
                             float* __restrict__ gcum) {
  int tid = threadIdx.x;
  int gw = blockIdx.x * 4 + (tid >> 6);  // h*1024 + l
  int lane = tid & 63;
  int l = gw & 1023, h = gw >> 10;
  size_t ix = (size_t)h * 16 + (l >> 6);
  float mp = mP[ix], np = nP[ix], gp = gP[ix];
  float ml = mloc[gw], nl = nloc[gw], gl = gloc[gw];
  float vp = vP[ix * 64 + lane];
  float vl = vloc[(size_t)gw * 64 + lane];
  float mf = fmaxf(mp, ml);
  float ep = expf(mp - mf), el = expf(ml - mf);
  float nf = np * ep + nl * el;
  float vf = vp * ep + vl * el;
  float inv = 1.f / (nf + 1e-5f);
  lin[(size_t)gw * 64 + lane] = vf * inv;
  if (lane == 0) {
    wts[gw] = expf(sim[gw] - mf) * inv;
    gcum[gw] = gp + gl;
  }
}

// ---------------- per-(h,chunk) outer-product partial state ----------------
__global__ void chunk_outer_k(const float* __restrict__ vn, const float* __restrict__ kn,
                              const float* __restrict__ gz, float* __restrict__ Mc) {
  __shared__ float vns[64][64], kns[64][64], gzs[64];
  int c = blockIdx.x, h = blockIdx.y, tid = threadIdx.x;
  size_t base = ((size_t)h * 1024 + c * 64) * 64;
#pragma unroll
  for (int i = 0; i < 16; i++) {
    int e = i * 256 + tid;
    vns[e >> 6][e & 63] = vn[base + e];
    kns[e >> 6][e & 63] = kn[base + e];
  }
  if (tid < 64) gzs[tid] = gz[h * 1024 + c * 64 + tid];
  __syncthreads();
  float acc[16] = {};
  for (int s = 0; s < 64; s++) {
    float g = gzs[s];
#pragma unroll
    for (int i = 0; i < 16; i++) {
      int pn = i * 256 + tid;
      acc[i] += (g * vns[s][pn >> 6]) * kns[s][pn & 63];
    }
  }
  size_t ob = (size_t)(h * 16 + c) * 4096;
#pragma unroll
  for (int i = 0; i < 16; i++) Mc[ob + i * 256 + tid] = acc[i];
}

// ---------------- exclusive prefix over chunks ----------------
__global__ void chunk_prefix_k(const float* __restrict__ Mc, float* __restrict__ Sb) {
  int idx = blockIdx.x * 256 + threadIdx.x;  // 16*4096
  int h = idx >> 12, pn = idx & 4095;
  float a = 0.f;
  for (int c = 0; c < 16; c++) {
    size_t o = (size_t)(h * 16 + c) * 4096 + pn;
    Sb[o] = a; a += Mc[o];
  }
}

// ---------------- per-(h,chunk) gated linear attn + blend ----------------
__launch_bounds__(256)
__global__ void chunk_attn_k(const float* __restrict__ qh, const float* __restrict__ vn,
                             const float* __restrict__ kn, const float* __restrict__ gz,
                             const float* __restrict__ gcum, const float* __restrict__ Sb,
                             const float* __restrict__ wts, const float* __restrict__ lin,
                             const float* __restrict__ qs, const float* __restrict__ scale,
                             float* __restrict__ Yc) {
  __shared__ float qls[64][65], vls[64][65], kls[64][65], P[64][33], gzs[64];
  int c = blockIdx.x, h = blockIdx.y, tid = threadIdx.x;
  size_t base = ((size_t)h * 1024 + c * 64) * 64;
#pragma unroll
  for (int i = 0; i < 16; i++) {
    int e = i * 256 + tid;
    int r = e >> 6, cc = e & 63;
    qls[r][cc] = qh[base + e];
    vls[r][cc] = vn[base + e];
    kls[r][cc] = kn[base + e];
  }
  if (tid < 64) gzs[tid] = gz[h * 1024 + c * 64 + tid];
  __syncthreads();
  const float* S = Sb + ((size_t)h * 16 + c) * 4096;
  const int t0 = (tid >> 4) * 4, n0 = (tid & 15) * 4;
  float y[4][4] = {};
  // inter-chunk: q @ S_before
  for (int p = 0; p < 64; p++) {
    float av[4];
#pragma unroll
    for (int i2 = 0; i2 < 4; i2++) av[i2] = qls[t0 + i2][p];
    float4 bv = *(const float4*)(S + p * 64 + n0);
#pragma unroll
    for (int i2 = 0; i2 < 4; i2++) {
      y[i2][0] += av[i2] * bv.x; y[i2][1] += av[i2] * bv.y;
      y[i2][2] += av[i2] * bv.z; y[i2][3] += av[i2] * bv.w;
    }
  }
  // intra-chunk, two 32-wide s slabs
  const int tg = tid >> 3;
  const int s2b = (tid & 7) * 4;
  for (int s0 = 0; s0 < 64; s0 += 32) {
    float pv[2][4] = {};
    for (int k2 = 0; k2 < 64; k2++) {
      float a0 = qls[tg * 2][k2], a1 = qls[tg * 2 + 1][k2];
#pragma unroll
      for (int j = 0; j < 4; j++) {
        float b = vls[s0 + s2b + j][k2];
        pv[0][j] += a0 * b;
        pv[1][j] += a1 * b;
      }
    }
#pragma unroll
    for (int ii = 0; ii < 2; ii++)
#pragma unroll
      for (int j = 0; j < 4; j++) {
        int t = tg * 2 + ii, ss = s0 + s2b + j;
        P[t][ss - s0] = (ss <= t) ? pv[ii][j] * gzs[ss] : 0.f;
      }
    __syncthreads();
    for (int ss = 0; ss < 32; ss++) {
      float pr[4], kv[4];
#pragma unroll
      for (int i2 = 0; i2 < 4; i2++) pr[i2] = P[t0 + i2][ss];
#pragma unroll
      for (int j = 0; j < 4; j++) kv[j] = kls[s0 + ss][n0 + j];
#pragma unroll
      for (int i2 = 0; i2 < 4; i2++)
#pragma unroll
        for (int j = 0; j < 4; j++) y[i2][j] += pr[i2] * kv[j];
    }
    __syncthreads();
  }
  float sc = scale[h];
#pragma unroll
  for (int i2 = 0; i2 < 4; i2++) {
    int l = c * 64 + t0 + i2;
    size_t il = (size_t)h * 1024 + l;
    float gcv = gcum[il], wv = wts[il], qv = qs[il];
    float den = 1.f / (gcv + 1e-5f);
#pragma unroll
    for (int j = 0; j < 4; j++) {
      float yb = sc * y[i2][j] * den;
      float yl = qv * lin[il * 64 + n0 + j];
      Yc[(size_t)l * 1024 + h * 64 + n0 + j] = yb + (yl - yb) * wv;
    }
  }
}

// ---------------- row l2norm over D=1024 + cast ----------------
__global__ void rownorm_cast_k(const float* __restrict__ Y, bf16* __restrict__ out) {
  __shared__ float red[4];
  int l = blockIdx.x, tid = threadIdx.x;
  float4 v = ((const float4*)(Y + (size_t)l * 1024))[tid];
  float ss = v.x * v.x + v.y * v.y + v.z * v.z + v.w * v.w;
  ss = wave_sum(ss);
  int wid = tid >> 6, lane = tid & 63;
  if (lane == 0) red[wid] = ss;
  __syncthreads();
  float tot = red[0] + red[1] + red[2] + red[3];
  float inv = 1.f / fmaxf(sqrtf(tot), 1e-12f);
  bf16x4 o;
  o.v[0] = __float2bfloat16(v.x * inv); o.v[1] = __float2bfloat16(v.y * inv);
  o.v[2] = __float2bfloat16(v.z * inv); o.v[3] = __float2bfloat16(v.w * inv);
  ((bf16x4*)(out + (size_t)l * 1024))[tid] = o;
}

// ======================================================================
extern "C" void kernel_launch(void* const* d_in, const int* in_sizes, int n_in,
                              void* d_out, int out_size, void* d_ws, size_t ws_size,
                              hipStream_t stream) {
  (void)in_sizes; (void)n_in; (void)out_size; (void)ws_size;
  const float* x     = (const float*)d_in[0];
  const float* basis = (const float*)d_in[1];
  const float* mphiW = (const float*)d_in[2];
  const float* mphiB = (const float*)d_in[3];
  const float* wqW = (const float*)d_in[4];  const float* wqB = (const float*)d_in[5];
  const float* wkW = (const float*)d_in[6];  const float* wkB = (const float*)d_in[7];
  const float* wvW = (const float*)d_in[8];  const float* wvB = (const float*)d_in[9];
  const float* woW = (const float*)d_in[10]; const float* woB = (const float*)d_in[11];
  const float* wgW = (const float*)d_in[12]; const float* wgB = (const float*)d_in[13];
  const float* kvs = (const float*)d_in[14];
  float* out = (float*)d_out;
  char* ws = (char*)d_ws;

  bf16*  pre     = (bf16*)(ws + 0x0000000UL);   // [1024][16384] bf16 (33.6M)
  bf16*  Tbuf    = (bf16*)(ws + 0x2000000UL);   // [16][1024][1024] bf16 (33.6M)
  float* part2   = (float*)(ws + 0x2000000UL);  // [8][1024][1024] f32, aliases Tbuf
  bf16*  mphi_bf = (bf16*)(ws + 0x4000000UL);   // [1024][16384] bf16
  float* qkvf    = (float*)(ws + 0x4000000UL);  // aliases mphi_bf (dead after stage2)
  bf16*  xt_b    = (bf16*)(ws + 0x6000000UL);   // XT [1024][1024] bf16
  bf16*  xtil_bf = (bf16*)(ws + 0x6200000UL);   // x_tilde bf16
  bf16*  wqkv_bf = (bf16*)(ws + 0x6400000UL);   // [3][1024][1024] bf16
  bf16*  wo_bf   = (bf16*)(ws + 0x6A00000UL);
  float* qkv_bias= (float*)(ws + 0x6C00000UL);
  float* qh      = (float*)(ws + 0x6C10000UL);  // [16][1024][64] f32
  float* kn      = (float*)(ws + 0x7010000UL);
  float* vn      = (float*)(ws + 0x7410000UL);
  float* lin     = (float*)(ws + 0x7810000UL);
  float* Mc      = (float*)(ws + 0x7C10000UL);  // [16][16][4096]
  float* Sb      = (float*)(ws + 0x8010000UL);
  float* Yc      = (float*)(ws + 0x8410000UL);  // [1024][1024] f32
  bf16*  ynorm   = (bf16*)(ws + 0x8810000UL);
  float* simb    = (float*)(ws + 0x8A10000UL);
  float* gzb     = (float*)(ws + 0x8A20000UL);
  float* qsb     = (float*)(ws + 0x8A30000UL);
  float* wtb     = (float*)(ws + 0x8A40000UL);
  float* gcb     = (float*)(ws + 0x8A50000UL);
  // scan scratch: after stage4 the part2/Tbuf region is dead
  float* vloc = (float*)(ws + 0x2000000UL);  // [16,1024,64] (4MB)
  float* mloc = (float*)(ws + 0x2400000UL);  // [16,1024]
  float* nloc = (float*)(ws + 0x2410000UL);
  float* gloc = (float*)(ws + 0x2420000UL);
  float* mA   = (float*)(ws + 0x2430000UL);  // [16,16]
  float* nA   = (float*)(ws + 0x2431000UL);
  float* gA   = (float*)(ws + 0x2432000UL);
  float* vA   = (float*)(ws + 0x2440000UL);  // [16,16,64]
  float* mP   = (float*)(ws + 0x2450000UL);
  float* nP   = (float*)(ws + 0x2451000UL);
  float* gP   = (float*)(ws + 0x2452000UL);
  float* vP   = (float*)(ws + 0x2460000UL);  // [16,16,64]

  // weight casts
  cast_bf16_k<<<8192, 256, 0, stream>>>(mphiW, mphi_bf, 2097152);
  cast_small_k<<<2060, 256, 0, stream>>>(wqW, wkW, wvW, woW, wqB, wkB, wvB,
                                         wqkv_bf, wo_bf, qkv_bias);
  transpose_cast_k<<<dim3(32, 32), 256, 0, stream>>>(x, xt_b);
  build_T_k<<<65536, 256, 0, stream>>>(basis, Tbuf);

  // stage1: pre[l][k*1024+d] = sum_s T_k[l][s] * x[s][d]  (triangular, batched over k)
  gemm_bt<1, 1, 0><<<dim3(8, 8, 16), 256, 0, stream>>>(
      Tbuf, 1048576L, 1024, xt_b, 0L, 1024, (void*)pre, 1024L, 16384,
      nullptr, 0, 1024, 1024, 1024);

  // stage2: x_tilde = pre @ M_phi_w^T (split-K x8)
  gemm_bt<0, 0, 0><<<dim3(8, 8, 8), 256, 0, stream>>>(
      pre, 2048L, 16384, mphi_bf, 2048L, 16384, (void*)part2, 1048576L, 1024,
      nullptr, 0, 1024, 1024, 2048);
  reduce8_k<<<4096, 256, 0, stream>>>(part2, mphiB, xtil_bf);

  // stage3: q,k,v
  gemm_bt<0, 0, 1><<<dim3(8, 8, 3), 256, 0, stream>>>(
      xtil_bf, 0L, 1024, wqkv_bf, 1048576L, 1024, (void*)qkvf, 1048576L, 1024,
      qkv_bias, 1024, 1024, 1024, 1024);

  // stage4: normalize k,v; sim; qsum; gates
  qkv_post_k<<<4096, 256, 0, stream>>>(qkvf, wgW, wgB, kvs, qh, kn, vn, simb, gzb, qsb);

  // stage5: parallel online-softmax scan + gate cumsum (3 phases)
  scan_local_k<<<dim3(16, 16), 64, 0, stream>>>(simb, gzb, vn, mloc, nloc, vloc, gloc,
                                                mA, nA, vA, gA);
  scan_combine_k<<<16, 64, 0, stream>>>(mA, nA, vA, gA, mP, nP, vP, gP);
  scan_apply_k<<<4096, 256, 0, stream>>>(mloc, nloc, vloc, gloc, mP, nP, vP, gP,
                                         simb, lin, wtb, gcb);

  // stage6: chunked gated linear attention + blend
  chunk_outer_k<<<dim3(16, 16), 256, 0, stream>>>(vn, kn, gzb, Mc);
  chunk_prefix_k<<<256, 256, 0, stream>>>(Mc, Sb);
  chunk_attn_k<<<dim3(16, 16), 256, 0, stream>>>(qh, vn, kn, gzb, gcb, Sb, wtb, lin, qsb, kvs, Yc);

  // stage7: row l2norm + cast
  rownorm_cast_k<<<1024, 256, 0, stream>>>(Yc, ynorm);

  // stage8: out = Ynorm @ wo^T + b
  gemm_bt<0, 0, 1><<<dim3(8, 8, 1), 256, 0, stream>>>(
      ynorm, 0L, 1024, wo_bf, 0L, 1024, (void*)out, 0L, 1024,
      woB, 0, 1024, 1024, 1024);
}

// Round 4
// 300.436 us; speedup vs baseline: 2.1898x; 1.1171x over previous
//
#include <hip/hip_runtime.h>
#include <hip/hip_bf16.h>

typedef __hip_bfloat16 bf16;
typedef __attribute__((ext_vector_type(8))) short short8;
typedef __attribute__((ext_vector_type(4))) float f32x4;

struct bf16x8 { bf16 v[8]; };
struct bf16x4 { bf16 v[4]; };

__device__ __forceinline__ void gload_lds16(const void* g, void* l) {
  __builtin_amdgcn_global_load_lds(
      (const __attribute__((address_space(1))) void*)g,
      (__attribute__((address_space(3))) void*)l, 16, 0, 0);
}

__device__ __forceinline__ float wave_sum(float x) {
#pragma unroll
  for (int o = 32; o > 0; o >>= 1) x += __shfl_xor(x, o, 64);
  return x;
}

// ---- fused prep: cast mphiW + wq/wk/wv/wo + pack qkv bias -----------------
__global__ void prep_cast_k(const float* __restrict__ mphiW,
                            const float* __restrict__ wq, const float* __restrict__ wk,
                            const float* __restrict__ wv, const float* __restrict__ wo,
                            const float* __restrict__ bq, const float* __restrict__ bk,
                            const float* __restrict__ bv,
                            bf16* __restrict__ mphi_bf, bf16* __restrict__ wqkv,
                            bf16* __restrict__ wo_bf, float* __restrict__ qkv_bias) {
  int b = blockIdx.x, tid = threadIdx.x;
  if (b < 8192) {
    int i = b * 256 + tid;
    const float4* p = (const float4*)mphiW + (size_t)i * 2;
    float4 a = p[0], c = p[1];
    bf16x8 o;
    o.v[0] = __float2bfloat16(a.x); o.v[1] = __float2bfloat16(a.y);
    o.v[2] = __float2bfloat16(a.z); o.v[3] = __float2bfloat16(a.w);
    o.v[4] = __float2bfloat16(c.x); o.v[5] = __float2bfloat16(c.y);
    o.v[6] = __float2bfloat16(c.z); o.v[7] = __float2bfloat16(c.w);
    ((bf16x8*)mphi_bf)[i] = o;
  } else if (b < 10240) {
    int bb = b - 8192;
    const float* src = (bb < 512) ? wq : (bb < 1024) ? wk : (bb < 1536) ? wv : wo;
    bf16* dst = (bb < 512) ? wqkv : (bb < 1024) ? (wqkv + 1048576)
               : (bb < 1536) ? (wqkv + 2097152) : wo_bf;
    int i = (bb & 511) * 256 + tid;
    const float4* p = (const float4*)src + (size_t)i * 2;
    float4 a = p[0], c = p[1];
    bf16x8 o;
    o.v[0] = __float2bfloat16(a.x); o.v[1] = __float2bfloat16(a.y);
    o.v[2] = __float2bfloat16(a.z); o.v[3] = __float2bfloat16(a.w);
    o.v[4] = __float2bfloat16(c.x); o.v[5] = __float2bfloat16(c.y);
    o.v[6] = __float2bfloat16(c.z); o.v[7] = __float2bfloat16(c.w);
    ((bf16x8*)dst)[i] = o;
  } else {
    int i = (b - 10240) * 256 + tid;
    if (i < 3072) {
      const float* s = (i < 1024) ? bq : (i < 2048) ? bk : bv;
      qkv_bias[i] = s[i & 1023];
    }
  }
}

// ---------------- transpose-cast: XT[d][s] = x[s][d] (bf16) ----------------
__global__ void transpose_cast_k(const float* __restrict__ X, bf16* __restrict__ XT) {
  __shared__ float t[32][33];
  int bx = blockIdx.x, by = blockIdx.y;
  int tx = threadIdx.x & 31, ty = threadIdx.x >> 5;  // 32 x 8
#pragma unroll
  for (int r = ty; r < 32; r += 8)
    t[r][tx] = X[(size_t)(by * 32 + r) * 1024 + bx * 32 + tx];
  __syncthreads();
#pragma unroll
  for (int r = ty; r < 32; r += 8)
    XT[(size_t)(bx * 32 + r) * 1024 + by * 32 + tx] = __float2bfloat16(t[tx][r]);
}

// ---------------- T[k][l][s] = (s<=l) ? basis[l-s][k] : 0, 8/thread --------
__global__ void build_T_k(const float* __restrict__ basis, bf16* __restrict__ T) {
  size_t i8 = (size_t)blockIdx.x * 256 + threadIdx.x;  // 2M
  size_t i = i8 * 8;
  int s0 = (int)(i & 1023);
  int l = (int)((i >> 10) & 1023);
  int k = (int)(i >> 20);
  bf16x8 o;
#pragma unroll
  for (int j = 0; j < 8; j++) {
    int s = s0 + j;
    o.v[j] = (s <= l) ? __float2bfloat16(basis[(size_t)(l - s) * 16 + k])
                      : __float2bfloat16(0.f);
  }
  ((bf16x8*)T)[i8] = o;
}

// ---------------- MFMA GEMM, C = A @ B^T (+bias). 128x128 tile, BK=64 ------
// 1D grid with bijective XCD swizzle (nwg % 8 == 0, xy grid fixed 8x8).
// DBUF=1: double-buffered w/ counted vmcnt (for low-occupancy dispatches).
// DBUF=0: single-buffer 32KB (relies on 4+ blocks/CU implicit overlap).
template<int TRI, int OUTBF, int HASB, int DBUF>
__global__ void gemm_bt(const bf16* __restrict__ A, long sAb, int lda,
                        const bf16* __restrict__ B, long sBb, int ldb,
                        void* __restrict__ Cv, long sCb, int ldc,
                        const float* __restrict__ bias, int sbias, int K) {
  constexpr int NB = DBUF ? 2 : 1;
  __shared__ bf16 As[NB][128 * 64];
  __shared__ bf16 Bs[NB][128 * 64];
  const int tid = threadIdx.x;
  const int lane = tid & 63;
  const int wid = tid >> 6;
  const int wr = wid >> 1, wc = wid & 1;
  // XCD swizzle: hw block -> contiguous logical chunk per XCD
  const int cpx = gridDim.x >> 3;
  const int logical = (blockIdx.x & 7) * cpx + (blockIdx.x >> 3);
  const int bx = logical & 7, by = (logical >> 3) & 7, bz = logical >> 6;
  const int r0 = by * 128, c0 = bx * 128;
  const bf16* Ab = A + (size_t)bz * sAb;
  const bf16* Bb = B + (size_t)bz * sBb;
  f32x4 acc[4][4] = {};
  const int kend = TRI ? min(K, r0 + 128) : K;
  const int nt = kend >> 6;

  const int srow = tid >> 3, scol = (tid & 7) << 3;

#define STAGE(buf, k0)                                                        \
  {                                                                           \
    _Pragma("unroll")                                                         \
    for (int i = 0; i < 4; i++) {                                             \
      int row = i * 32 + srow;                                                \
      gload_lds16(Ab + (size_t)(r0 + row) * lda + (k0) + scol,                \
                  &As[buf][(row << 6) + scol]);                               \
    }                                                                         \
    _Pragma("unroll")                                                         \
    for (int i = 0; i < 4; i++) {                                             \
      int row = i * 32 + srow;                                                \
      gload_lds16(Bb + (size_t)(c0 + row) * ldb + (k0) + scol,                \
                  &Bs[buf][(row << 6) + scol]);                               \
    }                                                                         \
  }

  int cur = 0;
  if (DBUF) STAGE(0, 0)
  for (int t = 0; t < nt; ++t) {
    if (DBUF) {
      if (t + 1 < nt) {
        STAGE(cur ^ 1, (t + 1) << 6)
        asm volatile("s_waitcnt vmcnt(8)" ::: "memory");
      } else {
        asm volatile("s_waitcnt vmcnt(0)" ::: "memory");
      }
      __syncthreads();
    } else {
      __syncthreads();
      STAGE(0, t << 6)
      asm volatile("s_waitcnt vmcnt(0)" ::: "memory");
      __syncthreads();
    }
#pragma unroll
    for (int ks = 0; ks < 2; ks++) {
      const int colo = ks * 32 + (lane >> 4) * 8;
      short8 af[4], bfr[4];
#pragma unroll
      for (int m = 0; m < 4; m++)
        af[m] = *(const short8*)&As[cur][(wr * 64 + m * 16 + (lane & 15)) * 64 + colo];
#pragma unroll
      for (int n = 0; n < 4; n++)
        bfr[n] = *(const short8*)&Bs[cur][(wc * 64 + n * 16 + (lane & 15)) * 64 + colo];
#pragma unroll
      for (int m = 0; m < 4; m++)
#pragma unroll
        for (int n = 0; n < 4; n++)
          acc[m][n] = __builtin_amdgcn_mfma_f32_16x16x32_bf16(af[m], bfr[n], acc[m][n], 0, 0, 0);
    }
    if (DBUF) { __syncthreads(); cur ^= 1; }
  }
#undef STAGE

  const int rb = r0 + wr * 64 + ((lane >> 4) << 2);
  const int cb = c0 + wc * 64 + (lane & 15);
#pragma unroll
  for (int n = 0; n < 4; n++) {
    const int col = cb + n * 16;
    float bv = HASB ? bias[bz * sbias + col] : 0.f;
#pragma unroll
    for (int m = 0; m < 4; m++) {
#pragma unroll
      for (int j = 0; j < 4; j++) {
        const int row = rb + m * 16 + j;
        size_t off = (size_t)bz * sCb + (size_t)row * ldc + col;
        float v = acc[m][n][j] + bv;
        if (OUTBF) ((bf16*)Cv)[off] = __float2bfloat16(v);
        else       ((float*)Cv)[off] = v;
      }
    }
  }
}

// ---------------- split-K x8 reduce + bias + cast ----------------
__global__ void reduce8_k(const float* __restrict__ p, const float* __restrict__ bias,
                          bf16* __restrict__ out) {
  int i = blockIdx.x * 256 + threadIdx.x;
  float v = bias[i & 1023];
#pragma unroll
  for (int j = 0; j < 8; j++) v += p[i + j * 1048576];
  out[i] = __float2bfloat16(v);
}

// ---------------- per-(h,l): l2norm k,v; sim; qsum; gate ----------------
__global__ void qkv_post_k(const float* __restrict__ qkv, const float* __restrict__ W,
                           const float* __restrict__ wgb, const float* __restrict__ scale,
                           float* __restrict__ kn, float* __restrict__ vn,
                           float* __restrict__ sim, float* __restrict__ gz, float* __restrict__ qs) {
  __shared__ float Wl[64][65];
  int tid = threadIdx.x;
#pragma unroll
  for (int i = 0; i < 16; i++) {
    int c = i * 256 + tid;
    Wl[c >> 6][c & 63] = W[c];
  }
  __syncthreads();
  int lane = tid & 63;
  int gw = blockIdx.x * 4 + (tid >> 6);
  int h = gw >> 10, l = gw & 1023;
  const float* base = qkv + (size_t)l * 1024 + h * 64 + lane;
  float q = base[0];
  float k = base[1048576];
  float v = base[2097152];
  float knv = k * (1.f / fmaxf(sqrtf(wave_sum(k * k)), 1e-12f));
  float vnv = v * (1.f / fmaxf(sqrtf(wave_sum(v * v)), 1e-12f));
  float simv = wave_sum(q * knv);
  float qsv = wave_sum(q);
  float inner = 0.f;
#pragma unroll 8
  for (int n = 0; n < 64; n++)
    inner += Wl[lane][n] * __shfl(knv, n, 64);
  float gl = wave_sum(vnv * inner) * scale[h] + wgb[0];
  float yy = gl > 0.f ? gl : 0.01f * gl;
  float gzz = yy * yy + 1e-5f;
  size_t o = ((size_t)h * 1024 + l) * 64 + lane;
  kn[o] = knv; vn[o] = vnv;
  if (lane == 0) {
    sim[h * 1024 + l] = simv; gz[h * 1024 + l] = gzz; qs[h * 1024 + l] = qsv;
  }
}

// ---------------- parallel online-softmax scan: phase 1 (per-chunk local) --
__global__ void scan_local_k(const float* __restrict__ sim, const float* __restrict__ gz,
                             const float* __restrict__ vn,
                             float* __restrict__ mloc, float* __restrict__ nloc,
                             float* __restrict__ vloc, float* __restrict__ gloc,
                             float* __restrict__ mA, float* __restrict__ nA,
                             float* __restrict__ vA, float* __restrict__ gA) {
  int c = blockIdx.x, h = blockIdx.y, lane = threadIdx.x;
  size_t hb = (size_t)h * 1024 + c * 64;
  float m = -1e30f, n = 0.f, v = 0.f, g = 0.f;
  for (int i = 0; i < 64; i++) {
    float s = sim[hb + i];
    float gg = gz[hb + i];
    float vv = vn[(hb + i) * 64 + lane];
    float mn = fmaxf(m, s);
    float eo = expf(m - mn);
    float en = expf(s - mn);
    n = n * eo + en;
    v = v * eo + en * vv;
    m = mn;
    g += gg;
    vloc[(hb + i) * 64 + lane] = v;
    if (lane == 0) { mloc[hb + i] = m; nloc[hb + i] = n; gloc[hb + i] = g; }
  }
  size_t ix = (size_t)h * 16 + c;
  vA[ix * 64 + lane] = v;
  if (lane == 0) { mA[ix] = m; nA[ix] = n; gA[ix] = g; }
}

// ---- phase 2+3 fused: per-(c,h) block recomputes head prefix, applies -----
__global__ void scan_apply_k(const float* __restrict__ mloc, const float* __restrict__ nloc,
                             const float* __restrict__ vloc, const float* __restrict__ gloc,
                             const float* __restrict__ mA, const float* __restrict__ nA,
                             const float* __restrict__ vA, const float* __restrict__ gA,
                             const float* __restrict__ sim,
                             float* __restrict__ lin, float* __restrict__ wts,
                             float* __restrict__ gcum) {
  int c = blockIdx.x, h = blockIdx.y;
  int tid = threadIdx.x, lane = tid & 63, w = tid >> 6;
  // exclusive prefix over chunk aggregates < c (redundant across waves)
  float m = -1e30f, n = 0.f, v = 0.f, g = 0.f;
  for (int cc = 0; cc < c; cc++) {
    size_t ix = (size_t)h * 16 + cc;
    float mb = mA[ix], nb = nA[ix], gb = gA[ix];
    float vb = vA[ix * 64 + lane];
    float mn = fmaxf(m, mb);
    float ea = expf(m - mn), eb = expf(mb - mn);
    n = n * ea + nb * eb;
    v = v * ea + vb * eb;
    m = mn; g += gb;
  }
#pragma unroll 4
  for (int i = 0; i < 16; i++) {
    int l = c * 64 + w * 16 + i;
    int gw = h * 1024 + l;
    float ml = mloc[gw], nl = nloc[gw], gl = gloc[gw];
    float vl = vloc[(size_t)gw * 64 + lane];
    float mf = fmaxf(m, ml);
    float ep = expf(m - mf), el = expf(ml - mf);
    float nf = n * ep + nl * el;
    float vf = v * ep + vl * el;
    float inv = 1.f / (nf + 1e-5f);
    lin[(size_t)gw * 64 + lane] = vf * inv;
    if (lane == 0) {
      wts[gw] = expf(sim[gw] - mf) * inv;
      gcum[gw] = g + gl;
    }
  }
}

// ---------------- per-(h,chunk) outer-product partial state ----------------
__global__ void chunk_outer_k(const float* __restrict__ vn, const float* __restrict__ kn,
                              const float* __restrict__ gz, float* __restrict__ Mc) {
  __shared__ float vns[64][64], kns[64][64], gzs[64];
  int c = blockIdx.x, h = blockIdx.y, tid = threadIdx.x;
  size_t base = ((size_t)h * 1024 + c * 64) * 64;
#pragma unroll
  for (int i = 0; i < 16; i++) {
    int e = i * 256 + tid;
    vns[e >> 6][e & 63] = vn[base + e];
    kns[e >> 6][e & 63] = kn[base + e];
  }
  if (tid < 64) gzs[tid] = gz[h * 1024 + c * 64 + tid];
  __syncthreads();
  float acc[16] = {};
  for (int s = 0; s < 64; s++) {
    float g = gzs[s];
#pragma unroll
    for (int i = 0; i < 16; i++) {
      int pn = i * 256 + tid;
      acc[i] += (g * vns[s][pn >> 6]) * kns[s][pn & 63];
    }
  }
  size_t ob = (size_t)(h * 16 + c) * 4096;
#pragma unroll
  for (int i = 0; i < 16; i++) Mc[ob + i * 256 + tid] = acc[i];
}

// ---------------- exclusive prefix over chunks ----------------
__global__ void chunk_prefix_k(const float* __restrict__ Mc, float* __restrict__ Sb) {
  int idx = blockIdx.x * 256 + threadIdx.x;  // 16*4096
  int h = idx >> 12, pn = idx & 4095;
  float a = 0.f;
  for (int c = 0; c < 16; c++) {
    size_t o = (size_t)(h * 16 + c) * 4096 + pn;
    Sb[o] = a; a += Mc[o];
  }
}

// ---------------- per-(h,chunk) gated linear attn + blend ----------------
__launch_bounds__(256)
__global__ void chunk_attn_k(const float* __restrict__ qkvf, const float* __restrict__ vn,
                             const float* __restrict__ kn, const float* __restrict__ gz,
                             const float* __restrict__ gcum, const float* __restrict__ Sb,
                             const float* __restrict__ wts, const float* __restrict__ lin,
                             const float* __restrict__ qs, const float* __restrict__ scale,
                             float* __restrict__ Yc) {
  __shared__ float qls[64][65], vls[64][65], kls[64][65], P[64][33], gzs[64];
  int c = blockIdx.x, h = blockIdx.y, tid = threadIdx.x;
  size_t base = ((size_t)h * 1024 + c * 64) * 64;
#pragma unroll
  for (int i = 0; i < 16; i++) {
    int e = i * 256 + tid;
    int r = e >> 6, cc = e & 63;
    qls[r][cc] = qkvf[(size_t)(c * 64 + r) * 1024 + h * 64 + cc];
    vls[r][cc] = vn[base + e];
    kls[r][cc] = kn[base + e];
  }
  if (tid < 64) gzs[tid] = gz[h * 1024 + c * 64 + tid];
  __syncthreads();
  const float* S = Sb + ((size_t)h * 16 + c) * 4096;
  const int t0 = (tid >> 4) * 4, n0 = (tid & 15) * 4;
  float y[4][4] = {};
  // inter-chunk: q @ S_before
  for (int p = 0; p < 64; p++) {
    float av[4];
#pragma unroll
    for (int i2 = 0; i2 < 4; i2++) av[i2] = qls[t0 + i2][p];
    float4 bv = *(const float4*)(S + p * 64 + n0);
#pragma unroll
    for (int i2 = 0; i2 < 4; i2++) {
      y[i2][0] += av[i2] * bv.x; y[i2][1] += av[i2] * bv.y;
      y[i2][2] += av[i2] * bv.z; y[i2][3] += av[i2] * bv.w;
    }
  }
  // intra-chunk, two 32-wide s slabs
  const int tg = tid >> 3;
  const int s2b = (tid & 7) * 4;
  for (int s0 = 0; s0 < 64; s0 += 32) {
    float pv[2][4] = {};
    for (int k2 = 0; k2 < 64; k2++) {
      float a0 = qls[tg * 2][k2], a1 = qls[tg * 2 + 1][k2];
#pragma unroll
      for (int j = 0; j < 4; j++) {
        float b = vls[s0 + s2b + j][k2];
        pv[0][j] += a0 * b;
        pv[1][j] += a1 * b;
      }
    }
#pragma unroll
    for (int ii = 0; ii < 2; ii++)
#pragma unroll
      for (int j = 0; j < 4; j++) {
        int t = tg * 2 + ii, ss = s0 + s2b + j;
        P[t][ss - s0] = (ss <= t) ? pv[ii][j] * gzs[ss] : 0.f;
      }
    __syncthreads();
    for (int ss = 0; ss < 32; ss++) {
      float pr[4], kv[4];
#pragma unroll
      for (int i2 = 0; i2 < 4; i2++) pr[i2] = P[t0 + i2][ss];
#pragma unroll
      for (int j = 0; j < 4; j++) kv[j] = kls[s0 + ss][n0 + j];
#pragma unroll
      for (int i2 = 0; i2 < 4; i2++)
#pragma unroll
        for (int j = 0; j < 4; j++) y[i2][j] += pr[i2] * kv[j];
    }
    __syncthreads();
  }
  float sc = scale[h];
#pragma unroll
  for (int i2 = 0; i2 < 4; i2++) {
    int l = c * 64 + t0 + i2;
    size_t il = (size_t)h * 1024 + l;
    float gcv = gcum[il], wv = wts[il], qv = qs[il];
    float den = 1.f / (gcv + 1e-5f);
#pragma unroll
    for (int j = 0; j < 4; j++) {
      float yb = sc * y[i2][j] * den;
      float yl = qv * lin[il * 64 + n0 + j];
      Yc[(size_t)l * 1024 + h * 64 + n0 + j] = yb + (yl - yb) * wv;
    }
  }
}

// ---------------- row l2norm over D=1024 + cast ----------------
__global__ void rownorm_cast_k(const float* __restrict__ Y, bf16* __restrict__ out) {
  __shared__ float red[4];
  int l = blockIdx.x, tid = threadIdx.x;
  float4 v = ((const float4*)(Y + (size_t)l * 1024))[tid];
  float ss = v.x * v.x + v.y * v.y + v.z * v.z + v.w * v.w;
  ss = wave_sum(ss);
  int wid = tid >> 6, lane = tid & 63;
  if (lane == 0) red[wid] = ss;
  __syncthreads();
  float tot = red[0] + red[1] + red[2] + red[3];
  float inv = 1.f / fmaxf(sqrtf(tot), 1e-12f);
  bf16x4 o;
  o.v[0] = __float2bfloat16(v.x * inv); o.v[1] = __float2bfloat16(v.y * inv);
  o.v[2] = __float2bfloat16(v.z * inv); o.v[3] = __float2bfloat16(v.w * inv);
  ((bf16x4*)(out + (size_t)l * 1024))[tid] = o;
}

// ======================================================================
extern "C" void kernel_launch(void* const* d_in, const int* in_sizes, int n_in,
                              void* d_out, int out_size, void* d_ws, size_t ws_size,
                              hipStream_t stream) {
  (void)in_sizes; (void)n_in; (void)out_size; (void)ws_size;
  const float* x     = (const float*)d_in[0];
  const float* basis = (const float*)d_in[1];
  const float* mphiW = (const float*)d_in[2];
  const float* mphiB = (const float*)d_in[3];
  const float* wqW = (const float*)d_in[4];  const float* wqB = (const float*)d_in[5];
  const float* wkW = (const float*)d_in[6];  const float* wkB = (const float*)d_in[7];
  const float* wvW = (const float*)d_in[8];  const float* wvB = (const float*)d_in[9];
  const float* woW = (const float*)d_in[10]; const float* woB = (const float*)d_in[11];
  const float* wgW = (const float*)d_in[12]; const float* wgB = (const float*)d_in[13];
  const float* kvs = (const float*)d_in[14];
  float* out = (float*)d_out;
  char* ws = (char*)d_ws;

  bf16*  pre     = (bf16*)(ws + 0x0000000UL);   // [1024][16384] bf16 (33.6M)
  bf16*  Tbuf    = (bf16*)(ws + 0x2000000UL);   // [16][1024][1024] bf16 (33.6M)
  float* part2   = (float*)(ws + 0x2000000UL);  // [8][1024][1024] f32, aliases Tbuf
  bf16*  mphi_bf = (bf16*)(ws + 0x4000000UL);   // [1024][16384] bf16
  float* qkvf    = (float*)(ws + 0x4000000UL);  // aliases mphi_bf (dead after stage2)
  bf16*  xt_b    = (bf16*)(ws + 0x6000000UL);   // XT [1024][1024] bf16
  bf16*  xtil_bf = (bf16*)(ws + 0x6200000UL);   // x_tilde bf16
  bf16*  wqkv_bf = (bf16*)(ws + 0x6400000UL);   // [3][1024][1024] bf16
  bf16*  wo_bf   = (bf16*)(ws + 0x6A00000UL);
  float* qkv_bias= (float*)(ws + 0x6C00000UL);
  float* kn      = (float*)(ws + 0x7010000UL);
  float* vn      = (float*)(ws + 0x7410000UL);
  float* lin     = (float*)(ws + 0x7810000UL);
  float* Mc      = (float*)(ws + 0x7C10000UL);  // [16][16][4096]
  float* Sb      = (float*)(ws + 0x8010000UL);
  float* Yc      = (float*)(ws + 0x8410000UL);  // [1024][1024] f32
  bf16*  ynorm   = (bf16*)(ws + 0x8810000UL);
  float* simb    = (float*)(ws + 0x8A10000UL);
  float* gzb     = (float*)(ws + 0x8A20000UL);
  float* qsb     = (float*)(ws + 0x8A30000UL);
  float* wtb     = (float*)(ws + 0x8A40000UL);
  float* gcb     = (float*)(ws + 0x8A50000UL);
  // scan scratch: after stage4 the part2/Tbuf region is dead
  float* vloc = (float*)(ws + 0x2000000UL);  // [16,1024,64] (4MB)
  float* mloc = (float*)(ws + 0x2400000UL);  // [16,1024]
  float* nloc = (float*)(ws + 0x2410000UL);
  float* gloc = (float*)(ws + 0x2420000UL);
  float* mA   = (float*)(ws + 0x2430000UL);  // [16,16]
  float* nA   = (float*)(ws + 0x2431000UL);
  float* gA   = (float*)(ws + 0x2432000UL);
  float* vA   = (float*)(ws + 0x2440000UL);  // [16,16,64]

  // prep: all weight casts + bias pack in one launch
  prep_cast_k<<<10252, 256, 0, stream>>>(mphiW, wqW, wkW, wvW, woW, wqB, wkB, wvB,
                                         mphi_bf, wqkv_bf, wo_bf, qkv_bias);
  transpose_cast_k<<<dim3(32, 32), 256, 0, stream>>>(x, xt_b);
  build_T_k<<<8192, 256, 0, stream>>>(basis, Tbuf);

  // stage1: pre = T_k @ x (triangular, batched over k). 1024 blocks, no-dbuf.
  gemm_bt<1, 1, 0, 0><<<1024, 256, 0, stream>>>(
      Tbuf, 1048576L, 1024, xt_b, 0L, 1024, (void*)pre, 1024L, 16384,
      nullptr, 0, 1024);

  // stage2: x_tilde = pre @ M_phi_w^T (split-K x8), dbuf + XCD swizzle
  gemm_bt<0, 0, 0, 1><<<512, 256, 0, stream>>>(
      pre, 2048L, 16384, mphi_bf, 2048L, 16384, (void*)part2, 1048576L, 1024,
      nullptr, 0, 2048);
  reduce8_k<<<4096, 256, 0, stream>>>(part2, mphiB, xtil_bf);

  // stage3: q,k,v
  gemm_bt<0, 0, 1, 1><<<192, 256, 0, stream>>>(
      xtil_bf, 0L, 1024, wqkv_bf, 1048576L, 1024, (void*)qkvf, 1048576L, 1024,
      qkv_bias, 1024, 1024);

  // stage4: normalize k,v; sim; qsum; gates
  qkv_post_k<<<4096, 256, 0, stream>>>(qkvf, wgW, wgB, kvs, kn, vn, simb, gzb, qsb);

  // stage5: parallel online-softmax scan + gate cumsum (2 launches)
  scan_local_k<<<dim3(16, 16), 64, 0, stream>>>(simb, gzb, vn, mloc, nloc, vloc, gloc,
                                                mA, nA, vA, gA);
  scan_apply_k<<<dim3(16, 16), 256, 0, stream>>>(mloc, nloc, vloc, gloc, mA, nA, vA, gA,
                                                 simb, lin, wtb, gcb);

  // stage6: chunked gated linear attention + blend
  chunk_outer_k<<<dim3(16, 16), 256, 0, stream>>>(vn, kn, gzb, Mc);
  chunk_prefix_k<<<256, 256, 0, stream>>>(Mc, Sb);
  chunk_attn_k<<<dim3(16, 16), 256, 0, stream>>>(qkvf, vn, kn, gzb, gcb, Sb, wtb, lin, qsb, kvs, Yc);

  // stage7: row l2norm + cast
  rownorm_cast_k<<<1024, 256, 0, stream>>>(Yc, ynorm);

  // stage8: out = Ynorm @ wo^T + b
  gemm_bt<0, 0, 1, 1><<<64, 256, 0, stream>>>(
      ynorm, 0L, 1024, wo_bf, 0L, 1024, (void*)out, 0L, 1024,
      woB, 0, 1024);
}

// Round 5
// 299.739 us; speedup vs baseline: 2.1949x; 1.0023x over previous
//
#include <hip/hip_runtime.h>
#include <hip/hip_bf16.h>

typedef __hip_bfloat16 bf16;
typedef __attribute__((ext_vector_type(8))) short short8;
typedef __attribute__((ext_vector_type(4))) float f32x4;

struct bf16x8 { bf16 v[8]; };
struct bf16x4 { bf16 v[4]; };

__device__ __forceinline__ void gload_lds16(const void* g, void* l) {
  __builtin_amdgcn_global_load_lds(
      (const __attribute__((address_space(1))) void*)g,
      (__attribute__((address_space(3))) void*)l, 16, 0, 0);
}

__device__ __forceinline__ float wave_sum(float x) {
#pragma unroll
  for (int o = 32; o > 0; o >>= 1) x += __shfl_xor(x, o, 64);
  return x;
}

// ---- fused prep: cast mphiW + wq/wk/wv/wo + x + pack qkv bias -------------
__global__ void prep_cast_k(const float* __restrict__ mphiW,
                            const float* __restrict__ wq, const float* __restrict__ wk,
                            const float* __restrict__ wv, const float* __restrict__ wo,
                            const float* __restrict__ x,
                            const float* __restrict__ bq, const float* __restrict__ bk,
                            const float* __restrict__ bv,
                            bf16* __restrict__ mphi_bf, bf16* __restrict__ wqkv,
                            bf16* __restrict__ wo_bf, bf16* __restrict__ x_bf,
                            float* __restrict__ qkv_bias) {
  int b = blockIdx.x, tid = threadIdx.x;
  const float* src; bf16* dst; int i;
  if (b < 8192) { src = mphiW; dst = mphi_bf; i = b * 256 + tid; }
  else if (b < 10240) {
    int bb = b - 8192;
    src = (bb < 512) ? wq : (bb < 1024) ? wk : (bb < 1536) ? wv : wo;
    dst = (bb < 512) ? wqkv : (bb < 1024) ? (wqkv + 1048576)
         : (bb < 1536) ? (wqkv + 2097152) : wo_bf;
    i = (bb & 511) * 256 + tid;
  } else if (b < 10752) { src = x; dst = x_bf; i = (b - 10240) * 256 + tid; }
  else {
    int j = (b - 10752) * 256 + tid;
    if (j < 3072) {
      const float* s = (j < 1024) ? bq : (j < 2048) ? bk : bv;
      qkv_bias[j] = s[j & 1023];
    }
    return;
  }
  const float4* p = (const float4*)src + (size_t)i * 2;
  float4 a = p[0], c = p[1];
  bf16x8 o;
  o.v[0] = __float2bfloat16(a.x); o.v[1] = __float2bfloat16(a.y);
  o.v[2] = __float2bfloat16(a.z); o.v[3] = __float2bfloat16(a.w);
  o.v[4] = __float2bfloat16(c.x); o.v[5] = __float2bfloat16(c.y);
  o.v[6] = __float2bfloat16(c.z); o.v[7] = __float2bfloat16(c.w);
  ((bf16x8*)dst)[i] = o;
}

// ---------------- T[k][l][s] = (s<=l) ? basis[l-s][k] : 0, 8/thread --------
__global__ void build_T_k(const float* __restrict__ basis, bf16* __restrict__ T) {
  size_t i8 = (size_t)blockIdx.x * 256 + threadIdx.x;  // 2M
  size_t i = i8 * 8;
  int s0 = (int)(i & 1023);
  int l = (int)((i >> 10) & 1023);
  int k = (int)(i >> 20);
  bf16x8 o;
#pragma unroll
  for (int j = 0; j < 8; j++) {
    int s = s0 + j;
    o.v[j] = (s <= l) ? __float2bfloat16(basis[(size_t)(l - s) * 16 + k])
                      : __float2bfloat16(0.f);
  }
  ((bf16x8*)T)[i8] = o;
}

// ---------------- MFMA GEMM, C = A @ B^T (+bias). 128x128 tile, BK=64 ------
// 1D grid, bijective XCD swizzle (gridDim.x % 8 == 0, xy tile grid fixed 8x8).
// TRI=0 dense; TRI=1 kend=r0+128; TRI=2 two-panel triangular (panel stride
// sPan, per-panel kend=min(K,r0+128), batch stride sAb/sBb covers 2 panels).
// DBUF=1: double-buffered + counted vmcnt. DBUF=0: single 32KB buffer
// (4+ blocks/CU implicit overlap regime).
template<int TRI, int OUTBF, int HASB, int DBUF>
__global__ void gemm_bt(const bf16* __restrict__ A, long sAb, int lda,
                        const bf16* __restrict__ B, long sBb, int ldb,
                        void* __restrict__ Cv, long sCb, int ldc,
                        const float* __restrict__ bias, int sbias,
                        long sPan, int K) {
  constexpr int NB = DBUF ? 2 : 1;
  __shared__ bf16 As[NB][128 * 64];
  __shared__ bf16 Bs[NB][128 * 64];
  const int tid = threadIdx.x;
  const int lane = tid & 63;
  const int wid = tid >> 6;
  const int wr = wid >> 1, wc = wid & 1;
  const int cpx = gridDim.x >> 3;
  const int logical = (blockIdx.x & 7) * cpx + (blockIdx.x >> 3);
  const int bx = logical & 7, by = (logical >> 3) & 7, bz = logical >> 6;
  const int r0 = by * 128, c0 = bx * 128;
  const bf16* Ab = A + (size_t)bz * sAb;
  const bf16* Bb = B + (size_t)bz * sBb;
  f32x4 acc[4][4] = {};
  int nt0, nt;
  if (TRI == 2)      { nt0 = min(K, r0 + 128) >> 6; nt = nt0 * 2; }
  else if (TRI == 1) { nt0 = 1 << 28; nt = min(K, r0 + 128) >> 6; }
  else               { nt0 = 1 << 28; nt = K >> 6; }

  const int srow = tid >> 3, scol = (tid & 7) << 3;

#define STAGE(buf, t)                                                         \
  {                                                                           \
    const int p_ = (TRI == 2 && (t) >= nt0) ? 1 : 0;                          \
    const int k0_ = ((t) - p_ * nt0) << 6;                                    \
    const bf16* Ab_ = Ab + (size_t)p_ * sPan;                                 \
    const bf16* Bb_ = Bb + (size_t)p_ * sPan;                                 \
    _Pragma("unroll")                                                         \
    for (int i = 0; i < 4; i++) {                                             \
      int row = i * 32 + srow;                                                \
      gload_lds16(Ab_ + (size_t)(r0 + row) * lda + k0_ + scol,                \
                  &As[buf][(row << 6) + scol]);                               \
    }                                                                         \
    _Pragma("unroll")                                                         \
    for (int i = 0; i < 4; i++) {                                             \
      int row = i * 32 + srow;                                                \
      gload_lds16(Bb_ + (size_t)(c0 + row) * ldb + k0_ + scol,                \
                  &Bs[buf][(row << 6) + scol]);                               \
    }                                                                         \
  }

  int cur = 0;
  if (DBUF) STAGE(0, 0)
  for (int t = 0; t < nt; ++t) {
    if (DBUF) {
      if (t + 1 < nt) {
        STAGE(cur ^ 1, t + 1)
        asm volatile("s_waitcnt vmcnt(8)" ::: "memory");
      } else {
        asm volatile("s_waitcnt vmcnt(0)" ::: "memory");
      }
      __syncthreads();
    } else {
      __syncthreads();
      STAGE(0, t)
      asm volatile("s_waitcnt vmcnt(0)" ::: "memory");
      __syncthreads();
    }
#pragma unroll
    for (int ks = 0; ks < 2; ks++) {
      const int colo = ks * 32 + (lane >> 4) * 8;
      short8 af[4], bfr[4];
#pragma unroll
      for (int m = 0; m < 4; m++)
        af[m] = *(const short8*)&As[cur][(wr * 64 + m * 16 + (lane & 15)) * 64 + colo];
#pragma unroll
      for (int n = 0; n < 4; n++)
        bfr[n] = *(const short8*)&Bs[cur][(wc * 64 + n * 16 + (lane & 15)) * 64 + colo];
#pragma unroll
      for (int m = 0; m < 4; m++)
#pragma unroll
        for (int n = 0; n < 4; n++)
          acc[m][n] = __builtin_amdgcn_mfma_f32_16x16x32_bf16(af[m], bfr[n], acc[m][n], 0, 0, 0);
    }
    if (DBUF) { __syncthreads(); cur ^= 1; }
  }
#undef STAGE

  const int rb = r0 + wr * 64 + ((lane >> 4) << 2);
  const int cb = c0 + wc * 64 + (lane & 15);
#pragma unroll
  for (int n = 0; n < 4; n++) {
    const int col = cb + n * 16;
    float bv = HASB ? bias[bz * sbias + col] : 0.f;
#pragma unroll
    for (int m = 0; m < 4; m++) {
#pragma unroll
      for (int j = 0; j < 4; j++) {
        const int row = rb + m * 16 + j;
        size_t off = (size_t)bz * sCb + (size_t)row * ldc + col;
        float v = acc[m][n][j] + bv;
        if (OUTBF) ((bf16*)Cv)[off] = __float2bfloat16(v);
        else       ((float*)Cv)[off] = v;
      }
    }
  }
}

// ---------------- split-K x8 reduce + bias + cast ----------------
__global__ void reduce8_k(const float* __restrict__ p, const float* __restrict__ bias,
                          bf16* __restrict__ out) {
  int i = blockIdx.x * 256 + threadIdx.x;
  float v = bias[i & 1023];
#pragma unroll
  for (int j = 0; j < 8; j++) v += p[i + j * 1048576];
  out[i] = __float2bfloat16(v);
}

// ---------------- per-(h,l): l2norm k,v; sim; qsum; gate ----------------
__global__ void qkv_post_k(const float* __restrict__ qkv, const float* __restrict__ W,
                           const float* __restrict__ wgb, const float* __restrict__ scale,
                           float* __restrict__ kn, float* __restrict__ vn,
                           float* __restrict__ sim, float* __restrict__ gz, float* __restrict__ qs) {
  __shared__ float Wl[64][65];
  int tid = threadIdx.x;
#pragma unroll
  for (int i = 0; i < 16; i++) {
    int c = i * 256 + tid;
    Wl[c >> 6][c & 63] = W[c];
  }
  __syncthreads();
  int lane = tid & 63;
  int gw = blockIdx.x * 4 + (tid >> 6);
  int h = gw >> 10, l = gw & 1023;
  const float* base = qkv + (size_t)l * 1024 + h * 64 + lane;
  float q = base[0];
  float k = base[1048576];
  float v = base[2097152];
  float knv = k * (1.f / fmaxf(sqrtf(wave_sum(k * k)), 1e-12f));
  float vnv = v * (1.f / fmaxf(sqrtf(wave_sum(v * v)), 1e-12f));
  float simv = wave_sum(q * knv);
  float qsv = wave_sum(q);
  float inner = 0.f;
#pragma unroll 8
  for (int n = 0; n < 64; n++)
    inner += Wl[lane][n] * __shfl(knv, n, 64);
  float gl = wave_sum(vnv * inner) * scale[h] + wgb[0];
  float yy = gl > 0.f ? gl : 0.01f * gl;
  float gzz = yy * yy + 1e-5f;
  size_t o = ((size_t)h * 1024 + l) * 64 + lane;
  kn[o] = knv; vn[o] = vnv;
  if (lane == 0) {
    sim[h * 1024 + l] = simv; gz[h * 1024 + l] = gzz; qs[h * 1024 + l] = qsv;
  }
}

// ---------------- parallel online-softmax scan: phase 1 (per-chunk local) --
__global__ void scan_local_k(const float* __restrict__ sim, const float* __restrict__ gz,
                             const float* __restrict__ vn,
                             float* __restrict__ mloc, float* __restrict__ nloc,
                             float* __restrict__ vloc, float* __restrict__ gloc,
                             float* __restrict__ mA, float* __restrict__ nA,
                             float* __restrict__ vA, float* __restrict__ gA) {
  int c = blockIdx.x, h = blockIdx.y, lane = threadIdx.x;
  size_t hb = (size_t)h * 1024 + c * 64;
  float m = -1e30f, n = 0.f, v = 0.f, g = 0.f;
  for (int i = 0; i < 64; i++) {
    float s = sim[hb + i];
    float gg = gz[hb + i];
    float vv = vn[(hb + i) * 64 + lane];
    float mn = fmaxf(m, s);
    float eo = expf(m - mn);
    float en = expf(s - mn);
    n = n * eo + en;
    v = v * eo + en * vv;
    m = mn;
    g += gg;
    vloc[(hb + i) * 64 + lane] = v;
    if (lane == 0) { mloc[hb + i] = m; nloc[hb + i] = n; gloc[hb + i] = g; }
  }
  size_t ix = (size_t)h * 16 + c;
  vA[ix * 64 + lane] = v;
  if (lane == 0) { mA[ix] = m; nA[ix] = n; gA[ix] = g; }
}

// ---- phase 2+3 fused: per-(c,h) block recomputes head prefix, applies -----
__global__ void scan_apply_k(const float* __restrict__ mloc, const float* __restrict__ nloc,
                             const float* __restrict__ vloc, const float* __restrict__ gloc,
                             const float* __restrict__ mA, const float* __restrict__ nA,
                             const float* __restrict__ vA, const float* __restrict__ gA,
                             const float* __restrict__ sim,
                             float* __restrict__ lin, float* __restrict__ wts,
                             float* __restrict__ gcum) {
  int c = blockIdx.x, h = blockIdx.y;
  int tid = threadIdx.x, lane = tid & 63, w = tid >> 6;
  float m = -1e30f, n = 0.f, v = 0.f, g = 0.f;
  for (int cc = 0; cc < c; cc++) {
    size_t ix = (size_t)h * 16 + cc;
    float mb = mA[ix], nb = nA[ix], gb = gA[ix];
    float vb = vA[ix * 64 + lane];
    float mn = fmaxf(m, mb);
    float ea = expf(m - mn), eb = expf(mb - mn);
    n = n * ea + nb * eb;
    v = v * ea + vb * eb;
    m = mn; g += gb;
  }
#pragma unroll 4
  for (int i = 0; i < 16; i++) {
    int l = c * 64 + w * 16 + i;
    int gw = h * 1024 + l;
    float ml = mloc[gw], nl = nloc[gw], gl = gloc[gw];
    float vl = vloc[(size_t)gw * 64 + lane];
    float mf = fmaxf(m, ml);
    float ep = expf(m - mf), el = expf(ml - mf);
    float nf = n * ep + nl * el;
    float vf = v * ep + vl * el;
    float inv = 1.f / (nf + 1e-5f);
    lin[(size_t)gw * 64 + lane] = vf * inv;
    if (lane == 0) {
      wts[gw] = expf(sim[gw] - mf) * inv;
      gcum[gw] = g + gl;
    }
  }
}

// ---------------- per-(h,chunk) outer-product partial state ----------------
__global__ void chunk_outer_k(const float* __restrict__ vn, const float* __restrict__ kn,
                              const float* __restrict__ gz, float* __restrict__ Mc) {
  __shared__ float vns[64][64], kns[64][64], gzs[64];
  int c = blockIdx.x, h = blockIdx.y, tid = threadIdx.x;
  size_t base = ((size_t)h * 1024 + c * 64) * 64;
#pragma unroll
  for (int i = 0; i < 16; i++) {
    int e = i * 256 + tid;
    vns[e >> 6][e & 63] = vn[base + e];
    kns[e >> 6][e & 63] = kn[base + e];
  }
  if (tid < 64) gzs[tid] = gz[h * 1024 + c * 64 + tid];
  __syncthreads();
  float acc[16] = {};
  for (int s = 0; s < 64; s++) {
    float g = gzs[s];
#pragma unroll
    for (int i = 0; i < 16; i++) {
      int pn = i * 256 + tid;
      acc[i] += (g * vns[s][pn >> 6]) * kns[s][pn & 63];
    }
  }
  size_t ob = (size_t)(h * 16 + c) * 4096;
#pragma unroll
  for (int i = 0; i < 16; i++) Mc[ob + i * 256 + tid] = acc[i];
}

// ---------------- exclusive prefix over chunks ----------------
__global__ void chunk_prefix_k(const float* __restrict__ Mc, float* __restrict__ Sb) {
  int idx = blockIdx.x * 256 + threadIdx.x;  // 16*4096
  int h = idx >> 12, pn = idx & 4095;
  float a = 0.f;
  for (int c = 0; c < 16; c++) {
    size_t o = (size_t)(h * 16 + c) * 4096 + pn;
    Sb[o] = a; a += Mc[o];
  }
}

// ---------------- per-(h,chunk) gated linear attn + blend ----------------
__launch_bounds__(256)
__global__ void chunk_attn_k(const float* __restrict__ qkvf, const float* __restrict__ vn,
                             const float* __restrict__ kn, const float* __restrict__ gz,
                             const float* __restrict__ gcum, const float* __restrict__ Sb,
                             const float* __restrict__ wts, const float* __restrict__ lin,
                             const float* __restrict__ qs, const float* __restrict__ scale,
                             float* __restrict__ Yc) {
  __shared__ float qls[64][65], vls[64][65], kls[64][68], P[64][33], gzs[64];
  int c = blockIdx.x, h = blockIdx.y, tid = threadIdx.x;
  size_t base = ((size_t)h * 1024 + c * 64) * 64;
#pragma unroll
  for (int i = 0; i < 16; i++) {
    int e = i * 256 + tid;
    int r = e >> 6, cc = e & 63;
    qls[r][cc] = qkvf[(size_t)(c * 64 + r) * 1024 + h * 64 + cc];
    vls[r][cc] = vn[base + e];
    kls[r][cc] = kn[base + e];
  }
  if (tid < 64) gzs[tid] = gz[h * 1024 + c * 64 + tid];
  __syncthreads();
  const float* S = Sb + ((size_t)h * 16 + c) * 4096;
  const int t0 = (tid >> 4) * 4, n0 = (tid & 15) * 4;
  float y[4][4] = {};
  // inter-chunk: q @ S_before
  for (int p = 0; p < 64; p++) {
    float av[4];
#pragma unroll
    for (int i2 = 0; i2 < 4; i2++) av[i2] = qls[t0 + i2][p];
    float4 bv = *(const float4*)(S + p * 64 + n0);
#pragma unroll
    for (int i2 = 0; i2 < 4; i2++) {
      y[i2][0] += av[i2] * bv.x; y[i2][1] += av[i2] * bv.y;
      y[i2][2] += av[i2] * bv.z; y[i2][3] += av[i2] * bv.w;
    }
  }
  // intra-chunk, two 32-wide s slabs
  const int tg = tid >> 3;
  const int s2b = (tid & 7) * 4;
  for (int s0 = 0; s0 < 64; s0 += 32) {
    float pv[2][4] = {};
    for (int k2 = 0; k2 < 64; k2++) {
      float a0 = qls[tg * 2][k2], a1 = qls[tg * 2 + 1][k2];
#pragma unroll
      for (int j = 0; j < 4; j++) {
        float b = vls[s0 + s2b + j][k2];
        pv[0][j] += a0 * b;
        pv[1][j] += a1 * b;
      }
    }
#pragma unroll
    for (int ii = 0; ii < 2; ii++)
#pragma unroll
      for (int j = 0; j < 4; j++) {
        int t = tg * 2 + ii, ss = s0 + s2b + j;
        P[t][ss - s0] = (ss <= t) ? pv[ii][j] * gzs[ss] : 0.f;
      }
    __syncthreads();
    for (int ss = 0; ss < 32; ss++) {
      float pr[4];
#pragma unroll
      for (int i2 = 0; i2 < 4; i2++) pr[i2] = P[t0 + i2][ss];
      float4 kvv = *(const float4*)&kls[s0 + ss][n0];
#pragma unroll
      for (int i2 = 0; i2 < 4; i2++) {
        y[i2][0] += pr[i2] * kvv.x; y[i2][1] += pr[i2] * kvv.y;
        y[i2][2] += pr[i2] * kvv.z; y[i2][3] += pr[i2] * kvv.w;
      }
    }
    __syncthreads();
  }
  float sc = scale[h];
#pragma unroll
  for (int i2 = 0; i2 < 4; i2++) {
    int l = c * 64 + t0 + i2;
    size_t il = (size_t)h * 1024 + l;
    float gcv = gcum[il], wv = wts[il], qv = qs[il];
    float den = 1.f / (gcv + 1e-5f);
#pragma unroll
    for (int j = 0; j < 4; j++) {
      float yb = sc * y[i2][j] * den;
      float yl = qv * lin[il * 64 + n0 + j];
      Yc[(size_t)l * 1024 + h * 64 + n0 + j] = yb + (yl - yb) * wv;
    }
  }
}

// ---------------- row l2norm over D=1024 + cast ----------------
__global__ void rownorm_cast_k(const float* __restrict__ Y, bf16* __restrict__ out) {
  __shared__ float red[4];
  int l = blockIdx.x, tid = threadIdx.x;
  float4 v = ((const float4*)(Y + (size_t)l * 1024))[tid];
  float ss = v.x * v.x + v.y * v.y + v.z * v.z + v.w * v.w;
  ss = wave_sum(ss);
  int wid = tid >> 6, lane = tid & 63;
  if (lane == 0) red[wid] = ss;
  __syncthreads();
  float tot = red[0] + red[1] + red[2] + red[3];
  float inv = 1.f / fmaxf(sqrtf(tot), 1e-12f);
  bf16x4 o;
  o.v[0] = __float2bfloat16(v.x * inv); o.v[1] = __float2bfloat16(v.y * inv);
  o.v[2] = __float2bfloat16(v.z * inv); o.v[3] = __float2bfloat16(v.w * inv);
  ((bf16x4*)(out + (size_t)l * 1024))[tid] = o;
}

// ======================================================================
extern "C" void kernel_launch(void* const* d_in, const int* in_sizes, int n_in,
                              void* d_out, int out_size, void* d_ws, size_t ws_size,
                              hipStream_t stream) {
  (void)in_sizes; (void)n_in; (void)out_size; (void)ws_size;
  const float* x     = (const float*)d_in[0];
  const float* basis = (const float*)d_in[1];
  const float* mphiW = (const float*)d_in[2];
  const float* mphiB = (const float*)d_in[3];
  const float* wqW = (const float*)d_in[4];  const float* wqB = (const float*)d_in[5];
  const float* wkW = (const float*)d_in[6];  const float* wkB = (const float*)d_in[7];
  const float* wvW = (const float*)d_in[8];  const float* wvB = (const float*)d_in[9];
  const float* woW = (const float*)d_in[10]; const float* woB = (const float*)d_in[11];
  const float* wgW = (const float*)d_in[12]; const float* wgB = (const float*)d_in[13];
  const float* kvs = (const float*)d_in[14];
  float* out = (float*)d_out;
  char* ws = (char*)d_ws;

  bf16*  Y_T     = (bf16*)(ws + 0x0000000UL);   // [16][1024 o][1024 s] bf16 (32MB)
  bf16*  Tbuf    = (bf16*)(ws + 0x2000000UL);   // [16][1024 l][1024 s] bf16 (32MB)
  bf16*  mphi_bf = (bf16*)(ws + 0x4000000UL);   // [1024][16384] bf16 (32MB)
  float* part2   = (float*)(ws + 0x4000000UL);  // [8][1024][1024] f32 (aliases mphi, dead after stage-A)
  float* qkvf    = (float*)(ws + 0x4000000UL);  // [3][1024][1024] f32 (aliases part2, dead after reduce8)
  bf16*  x_bf    = (bf16*)(ws + 0x6000000UL);   // X [1024 s][1024 d] bf16 (2MB)
  bf16*  xtil_bf = (bf16*)(ws + 0x6200000UL);   // x_tilde bf16
  bf16*  wqkv_bf = (bf16*)(ws + 0x6400000UL);   // [3][1024][1024] bf16
  bf16*  wo_bf   = (bf16*)(ws + 0x6A00000UL);
  float* qkv_bias= (float*)(ws + 0x6C00000UL);
  float* kn      = (float*)(ws + 0x7010000UL);
  float* vn      = (float*)(ws + 0x7410000UL);
  float* lin     = (float*)(ws + 0x7810000UL);
  float* Mc      = (float*)(ws + 0x7C10000UL);  // [16][16][4096]
  float* Sb      = (float*)(ws + 0x8010000UL);
  float* Yc      = (float*)(ws + 0x8410000UL);  // [1024][1024] f32
  bf16*  ynorm   = (bf16*)(ws + 0x8810000UL);
  float* simb    = (float*)(ws + 0x8A10000UL);
  float* gzb     = (float*)(ws + 0x8A20000UL);
  float* qsb     = (float*)(ws + 0x8A30000UL);
  float* wtb     = (float*)(ws + 0x8A40000UL);
  float* gcb     = (float*)(ws + 0x8A50000UL);
  // scan scratch: Tbuf region is dead after stage-B
  float* vloc = (float*)(ws + 0x2000000UL);  // [16,1024,64] (4MB)
  float* mloc = (float*)(ws + 0x2400000UL);
  float* nloc = (float*)(ws + 0x2410000UL);
  float* gloc = (float*)(ws + 0x2420000UL);
  float* mA   = (float*)(ws + 0x2430000UL);
  float* nA   = (float*)(ws + 0x2431000UL);
  float* gA   = (float*)(ws + 0x2432000UL);
  float* vA   = (float*)(ws + 0x2440000UL);  // [16,16,64]

  // prep: all weight/x casts + bias pack in one launch
  prep_cast_k<<<10764, 256, 0, stream>>>(mphiW, wqW, wkW, wvW, woW, x, wqB, wkB, wvB,
                                         mphi_bf, wqkv_bf, wo_bf, x_bf, qkv_bias);
  build_T_k<<<8192, 256, 0, stream>>>(basis, Tbuf);

  // stage-A: Y_T[k][o][s] = Mphi_k @ X^T  (16 batched dense GEMMs, K=1024)
  gemm_bt<0, 1, 0, 0><<<1024, 256, 0, stream>>>(
      mphi_bf, 1024L, 16384, x_bf, 0L, 1024, (void*)Y_T, 1048576L, 1024,
      nullptr, 0, 0L, 1024);

  // stage-B: x_tilde = sum_k T_k @ Y_T[k]^T  (triangular 2-panel, split-K x8)
  gemm_bt<2, 0, 0, 1><<<512, 256, 0, stream>>>(
      Tbuf, 2097152L, 1024, Y_T, 2097152L, 1024, (void*)part2, 1048576L, 1024,
      nullptr, 0, 1048576L, 1024);
  reduce8_k<<<4096, 256, 0, stream>>>(part2, mphiB, xtil_bf);

  // stage3: q,k,v
  gemm_bt<0, 0, 1, 1><<<192, 256, 0, stream>>>(
      xtil_bf, 0L, 1024, wqkv_bf, 1048576L, 1024, (void*)qkvf, 1048576L, 1024,
      qkv_bias, 1024, 0L, 1024);

  // stage4: normalize k,v; sim; qsum; gates
  qkv_post_k<<<4096, 256, 0, stream>>>(qkvf, wgW, wgB, kvs, kn, vn, simb, gzb, qsb);

  // stage5: parallel online-softmax scan + gate cumsum
  scan_local_k<<<dim3(16, 16), 64, 0, stream>>>(simb, gzb, vn, mloc, nloc, vloc, gloc,
                                                mA, nA, vA, gA);
  scan_apply_k<<<dim3(16, 16), 256, 0, stream>>>(mloc, nloc, vloc, gloc, mA, nA, vA, gA,
                                                 simb, lin, wtb, gcb);

  // stage6: chunked gated linear attention + blend
  chunk_outer_k<<<dim3(16, 16), 256, 0, stream>>>(vn, kn, gzb, Mc);
  chunk_prefix_k<<<256, 256, 0, stream>>>(Mc, Sb);
  chunk_attn_k<<<dim3(16, 16), 256, 0, stream>>>(qkvf, vn, kn, gzb, gcb, Sb, wtb, lin, qsb, kvs, Yc);

  // stage7: row l2norm + cast
  rownorm_cast_k<<<1024, 256, 0, stream>>>(Yc, ynorm);

  // stage8: out = Ynorm @ wo^T + b
  gemm_bt<0, 0, 1, 1><<<64, 256, 0, stream>>>(
      ynorm, 0L, 1024, wo_bf, 0L, 1024, (void*)out, 0L, 1024,
      woB, 0, 0L, 1024);
}

// Round 6
// 270.262 us; speedup vs baseline: 2.4343x; 1.1091x over previous
//
#include <hip/hip_runtime.h>
#include <hip/hip_bf16.h>

typedef __hip_bfloat16 bf16;
typedef __attribute__((ext_vector_type(8))) short short8;
typedef __attribute__((ext_vector_type(4))) float f32x4;

struct bf16x8 { bf16 v[8]; };
struct bf16x4 { bf16 v[4]; };

__device__ __forceinline__ void gload_lds16(const void* g, void* l) {
  __builtin_amdgcn_global_load_lds(
      (const __attribute__((address_space(1))) void*)g,
      (__attribute__((address_space(3))) void*)l, 16, 0, 0);
}

__device__ __forceinline__ float wave_sum(float x) {
#pragma unroll
  for (int o = 32; o > 0; o >>= 1) x += __shfl_xor(x, o, 64);
  return x;
}

// ---- fused prep: cast mphiW + wq/wk/wv/wo + x + pack qkv bias -------------
__global__ void prep_cast_k(const float* __restrict__ mphiW,
                            const float* __restrict__ wq, const float* __restrict__ wk,
                            const float* __restrict__ wv, const float* __restrict__ wo,
                            const float* __restrict__ x,
                            const float* __restrict__ bq, const float* __restrict__ bk,
                            const float* __restrict__ bv,
                            bf16* __restrict__ mphi_bf, bf16* __restrict__ wqkv,
                            bf16* __restrict__ wo_bf, bf16* __restrict__ x_bf,
                            float* __restrict__ qkv_bias) {
  int b = blockIdx.x, tid = threadIdx.x;
  const float* src; bf16* dst; int i;
  if (b < 8192) { src = mphiW; dst = mphi_bf; i = b * 256 + tid; }
  else if (b < 10240) {
    int bb = b - 8192;
    src = (bb < 512) ? wq : (bb < 1024) ? wk : (bb < 1536) ? wv : wo;
    dst = (bb < 512) ? wqkv : (bb < 1024) ? (wqkv + 1048576)
         : (bb < 1536) ? (wqkv + 2097152) : wo_bf;
    i = (bb & 511) * 256 + tid;
  } else if (b < 10752) { src = x; dst = x_bf; i = (b - 10240) * 256 + tid; }
  else {
    int j = (b - 10752) * 256 + tid;
    if (j < 3072) {
      const float* s = (j < 1024) ? bq : (j < 2048) ? bk : bv;
      qkv_bias[j] = s[j & 1023];
    }
    return;
  }
  const float4* p = (const float4*)src + (size_t)i * 2;
  float4 a = p[0], c = p[1];
  bf16x8 o;
  o.v[0] = __float2bfloat16(a.x); o.v[1] = __float2bfloat16(a.y);
  o.v[2] = __float2bfloat16(a.z); o.v[3] = __float2bfloat16(a.w);
  o.v[4] = __float2bfloat16(c.x); o.v[5] = __float2bfloat16(c.y);
  o.v[6] = __float2bfloat16(c.z); o.v[7] = __float2bfloat16(c.w);
  ((bf16x8*)dst)[i] = o;
}

// ---------------- T[k][l][s] = (s<=l) ? basis[l-s][k] : 0, 8/thread --------
__global__ void build_T_k(const float* __restrict__ basis, bf16* __restrict__ T) {
  size_t i8 = (size_t)blockIdx.x * 256 + threadIdx.x;  // 2M
  size_t i = i8 * 8;
  int s0 = (int)(i & 1023);
  int l = (int)((i >> 10) & 1023);
  int k = (int)(i >> 20);
  bf16x8 o;
#pragma unroll
  for (int j = 0; j < 8; j++) {
    int s = s0 + j;
    o.v[j] = (s <= l) ? __float2bfloat16(basis[(size_t)(l - s) * 16 + k])
                      : __float2bfloat16(0.f);
  }
  ((bf16x8*)T)[i8] = o;
}

// ---------------- MFMA GEMM, C = A @ B^T (+bias). 128x128 tile, BK=64 ------
// 1D grid, bijective XCD swizzle (gridDim.x % 8 == 0, xy tile grid fixed 8x8).
// TRI=1: kend = min(K, r0+128). Split output regions: bz < nbz1 -> Cv, else
// Cv2 (slab bz-nbz1). DBUF=1 double-buffered + counted vmcnt (low-occupancy
// dispatches); DBUF=0 single 32KB buffer (4+ blocks/CU implicit overlap).
template<int TRI, int OUTBF, int HASB, int DBUF>
__global__ void gemm_bt(const bf16* __restrict__ A, long sAb, int lda,
                        const bf16* __restrict__ B, long sBb, int ldb,
                        void* __restrict__ Cv, void* __restrict__ Cv2, int nbz1,
                        long sCb, int ldc,
                        const float* __restrict__ bias, int sbias, int K) {
  constexpr int NB = DBUF ? 2 : 1;
  __shared__ bf16 As[NB][128 * 64];
  __shared__ bf16 Bs[NB][128 * 64];
  const int tid = threadIdx.x;
  const int lane = tid & 63;
  const int wid = tid >> 6;
  const int wr = wid >> 1, wc = wid & 1;
  const int cpx = gridDim.x >> 3;
  const int logical = (blockIdx.x & 7) * cpx + (blockIdx.x >> 3);
  const int bx = logical & 7, by = (logical >> 3) & 7, bz = logical >> 6;
  const int r0 = by * 128, c0 = bx * 128;
  const bf16* Ab = A + (size_t)bz * sAb;
  const bf16* Bb = B + (size_t)bz * sBb;
  f32x4 acc[4][4] = {};
  const int nt = (TRI ? min(K, r0 + 128) : K) >> 6;

  const int srow = tid >> 3, scol = (tid & 7) << 3;

#define STAGE(buf, t)                                                         \
  {                                                                           \
    const int k0_ = (t) << 6;                                                 \
    _Pragma("unroll")                                                         \
    for (int i = 0; i < 4; i++) {                                             \
      int row = i * 32 + srow;                                                \
      gload_lds16(Ab + (size_t)(r0 + row) * lda + k0_ + scol,                 \
                  &As[buf][(row << 6) + scol]);                               \
    }                                                                         \
    _Pragma("unroll")                                                         \
    for (int i = 0; i < 4; i++) {                                             \
      int row = i * 32 + srow;                                                \
      gload_lds16(Bb + (size_t)(c0 + row) * ldb + k0_ + scol,                 \
                  &Bs[buf][(row << 6) + scol]);                               \
    }                                                                         \
  }

  int cur = 0;
  if (DBUF) STAGE(0, 0)
  for (int t = 0; t < nt; ++t) {
    if (DBUF) {
      if (t + 1 < nt) {
        STAGE(cur ^ 1, t + 1)
        asm volatile("s_waitcnt vmcnt(8)" ::: "memory");
      } else {
        asm volatile("s_waitcnt vmcnt(0)" ::: "memory");
      }
      __syncthreads();
    } else {
      __syncthreads();
      STAGE(0, t)
      asm volatile("s_waitcnt vmcnt(0)" ::: "memory");
      __syncthreads();
    }
#pragma unroll
    for (int ks = 0; ks < 2; ks++) {
      const int colo = ks * 32 + (lane >> 4) * 8;
      short8 af[4], bfr[4];
#pragma unroll
      for (int m = 0; m < 4; m++)
        af[m] = *(const short8*)&As[cur][(wr * 64 + m * 16 + (lane & 15)) * 64 + colo];
#pragma unroll
      for (int n = 0; n < 4; n++)
        bfr[n] = *(const short8*)&Bs[cur][(wc * 64 + n * 16 + (lane & 15)) * 64 + colo];
#pragma unroll
      for (int m = 0; m < 4; m++)
#pragma unroll
        for (int n = 0; n < 4; n++)
          acc[m][n] = __builtin_amdgcn_mfma_f32_16x16x32_bf16(af[m], bfr[n], acc[m][n], 0, 0, 0);
    }
    if (DBUF) { __syncthreads(); cur ^= 1; }
  }
#undef STAGE

  void* Cb = (bz < nbz1) ? Cv : Cv2;
  const int bzl = (bz < nbz1) ? bz : bz - nbz1;
  const int rb = r0 + wr * 64 + ((lane >> 4) << 2);
  const int cb = c0 + wc * 64 + (lane & 15);
#pragma unroll
  for (int n = 0; n < 4; n++) {
    const int col = cb + n * 16;
    float bv = HASB ? bias[bz * sbias + col] : 0.f;
#pragma unroll
    for (int m = 0; m < 4; m++) {
#pragma unroll
      for (int j = 0; j < 4; j++) {
        const int row = rb + m * 16 + j;
        size_t off = (size_t)bzl * sCb + (size_t)row * ldc + col;
        float v = acc[m][n][j] + bv;
        if (OUTBF) ((bf16*)Cb)[off] = __float2bfloat16(v);
        else       ((float*)Cb)[off] = v;
      }
    }
  }
}

// ---------------- split-K x16 reduce (two regions) + bias + cast -----------
__global__ void reduce16_k(const float* __restrict__ pA, const float* __restrict__ pB,
                           const float* __restrict__ bias, bf16* __restrict__ out) {
  int i4 = blockIdx.x * 256 + threadIdx.x;  // 256K float4s
  float4 v = *((const float4*)bias + (i4 & 255));
#pragma unroll
  for (int j = 0; j < 8; j++) {
    float4 a = *((const float4*)pA + i4 + j * 262144);
    v.x += a.x; v.y += a.y; v.z += a.z; v.w += a.w;
  }
#pragma unroll
  for (int j = 0; j < 8; j++) {
    float4 a = *((const float4*)pB + i4 + j * 262144);
    v.x += a.x; v.y += a.y; v.z += a.z; v.w += a.w;
  }
  bf16x4 o;
  o.v[0] = __float2bfloat16(v.x); o.v[1] = __float2bfloat16(v.y);
  o.v[2] = __float2bfloat16(v.z); o.v[3] = __float2bfloat16(v.w);
  ((bf16x4*)out)[i4] = o;
}

// ---------------- split-K x4 reduce + bias, f32 out ----------------
__global__ void reduce4f_k(const float* __restrict__ p, const float* __restrict__ bias,
                           float* __restrict__ out) {
  int i4 = blockIdx.x * 256 + threadIdx.x;  // 256K float4s
  float4 v = *((const float4*)bias + (i4 & 255));
#pragma unroll
  for (int j = 0; j < 4; j++) {
    float4 a = *((const float4*)p + i4 + j * 262144);
    v.x += a.x; v.y += a.y; v.z += a.z; v.w += a.w;
  }
  ((float4*)out)[i4] = v;
}

// ---------------- per-(h,l): l2norm k,v; sim; qsum; gate ----------------
__global__ void qkv_post_k(const float* __restrict__ qkv, const float* __restrict__ W,
                           const float* __restrict__ wgb, const float* __restrict__ scale,
                           float* __restrict__ kn, float* __restrict__ vn,
                           float* __restrict__ sim, float* __restrict__ gz, float* __restrict__ qs) {
  __shared__ float Wl[64][65];
  int tid = threadIdx.x;
#pragma unroll
  for (int i = 0; i < 16; i++) {
    int c = i * 256 + tid;
    Wl[c >> 6][c & 63] = W[c];
  }
  __syncthreads();
  int lane = tid & 63;
  int gw = blockIdx.x * 4 + (tid >> 6);
  int h = gw >> 10, l = gw & 1023;
  const float* base = qkv + (size_t)l * 1024 + h * 64 + lane;
  float q = base[0];
  float k = base[1048576];
  float v = base[2097152];
  float knv = k * (1.f / fmaxf(sqrtf(wave_sum(k * k)), 1e-12f));
  float vnv = v * (1.f / fmaxf(sqrtf(wave_sum(v * v)), 1e-12f));
  float simv = wave_sum(q * knv);
  float qsv = wave_sum(q);
  float inner = 0.f;
#pragma unroll 8
  for (int n = 0; n < 64; n++)
    inner += Wl[lane][n] * __shfl(knv, n, 64);
  float gl = wave_sum(vnv * inner) * scale[h] + wgb[0];
  float yy = gl > 0.f ? gl : 0.01f * gl;
  float gzz = yy * yy + 1e-5f;
  size_t o = ((size_t)h * 1024 + l) * 64 + lane;
  kn[o] = knv; vn[o] = vnv;
  if (lane == 0) {
    sim[h * 1024 + l] = simv; gz[h * 1024 + l] = gzz; qs[h * 1024 + l] = qsv;
  }
}

// ---- fused: per-(c,h) local softmax-scan + gated outer-product state ------
__global__ void scan_outer_k(const float* __restrict__ sim, const float* __restrict__ gz,
                             const float* __restrict__ vn, const float* __restrict__ kn,
                             float* __restrict__ vloc, float* __restrict__ mloc,
                             float* __restrict__ nloc, float* __restrict__ gloc,
                             float* __restrict__ mA, float* __restrict__ nA,
                             float* __restrict__ vA, float* __restrict__ gA,
                             float* __restrict__ Mc) {
  __shared__ float vns[64][64], kns[64][64], gzs[64];
  int c = blockIdx.x, h = blockIdx.y, tid = threadIdx.x;
  size_t base = ((size_t)h * 1024 + c * 64) * 64;
#pragma unroll
  for (int i = 0; i < 16; i++) {
    int e = i * 256 + tid;
    vns[e >> 6][e & 63] = vn[base + e];
    kns[e >> 6][e & 63] = kn[base + e];
  }
  if (tid < 64) gzs[tid] = gz[h * 1024 + c * 64 + tid];
  __syncthreads();
  // outer product (all 256 threads)
  float acc[16] = {};
  for (int s = 0; s < 64; s++) {
    float g = gzs[s];
#pragma unroll
    for (int i = 0; i < 16; i++) {
      int pn = i * 256 + tid;
      acc[i] += (g * vns[s][pn >> 6]) * kns[s][pn & 63];
    }
  }
  size_t ob = (size_t)(h * 16 + c) * 4096;
#pragma unroll
  for (int i = 0; i < 16; i++) Mc[ob + i * 256 + tid] = acc[i];
  // local online-softmax scan (wave 0; v data already in LDS)
  if (tid < 64) {
    int lane = tid;
    size_t hb = (size_t)h * 1024 + c * 64;
    float m = -1e30f, n = 0.f, v = 0.f, g = 0.f;
    for (int i = 0; i < 64; i++) {
      float s = sim[hb + i];
      float vv = vns[i][lane];
      float mn = fmaxf(m, s);
      float eo = expf(m - mn);
      float en = expf(s - mn);
      n = n * eo + en;
      v = v * eo + en * vv;
      m = mn;
      g += gzs[i];
      vloc[(hb + i) * 64 + lane] = v;
      if (lane == 0) { mloc[hb + i] = m; nloc[hb + i] = n; gloc[hb + i] = g; }
    }
    size_t ix = (size_t)h * 16 + c;
    vA[ix * 64 + lane] = v;
    if (lane == 0) { mA[ix] = m; nA[ix] = n; gA[ix] = g; }
  }
}

// ---- fused: per-(c,h) scan-apply + state prefix + gated attn + blend ------
__launch_bounds__(256)
__global__ void apply_attn_k(const float* __restrict__ qkvf, const float* __restrict__ vn,
                             const float* __restrict__ kn, const float* __restrict__ gz,
                             const float* __restrict__ sim, const float* __restrict__ qs,
                             const float* __restrict__ mloc, const float* __restrict__ nloc,
                             const float* __restrict__ gloc, const float* __restrict__ vloc,
                             const float* __restrict__ mA, const float* __restrict__ nA,
                             const float* __restrict__ gA, const float* __restrict__ vA,
                             const float* __restrict__ Mc, const float* __restrict__ scale,
                             float* __restrict__ Yc) {
  __shared__ float qls[64][65], vls[64][65], kls[64][68], P[64][33];
  __shared__ float S[4096], lin_s[64][68];
  __shared__ float gzs[64], wt_s[64], gc_s[64];
  int c = blockIdx.x, h = blockIdx.y, tid = threadIdx.x;
  size_t base = ((size_t)h * 1024 + c * 64) * 64;
#pragma unroll
  for (int i = 0; i < 16; i++) {
    int e = i * 256 + tid;
    int r = e >> 6, cc = e & 63;
    qls[r][cc] = qkvf[(size_t)(c * 64 + r) * 1024 + h * 64 + cc];
    vls[r][cc] = vn[base + e];
    kls[r][cc] = kn[base + e];
  }
  if (tid < 64) gzs[tid] = gz[h * 1024 + c * 64 + tid];
  // exclusive prefix of gated state over chunks < c (from Mc, L2-resident)
  {
    float4 a0 = {0,0,0,0}, a1 = {0,0,0,0}, a2 = {0,0,0,0}, a3 = {0,0,0,0};
    const float* McH = Mc + (size_t)h * 16 * 4096;
    for (int cc = 0; cc < c; cc++) {
      const float4* p = (const float4*)(McH + cc * 4096) + tid * 4;
      float4 t0 = p[0], t1 = p[1], t2 = p[2], t3 = p[3];
      a0.x += t0.x; a0.y += t0.y; a0.z += t0.z; a0.w += t0.w;
      a1.x += t1.x; a1.y += t1.y; a1.z += t1.z; a1.w += t1.w;
      a2.x += t2.x; a2.y += t2.y; a2.z += t2.z; a2.w += t2.w;
      a3.x += t3.x; a3.y += t3.y; a3.z += t3.z; a3.w += t3.w;
    }
    float4* Sp = (float4*)S + tid * 4;
    Sp[0] = a0; Sp[1] = a1; Sp[2] = a2; Sp[3] = a3;
  }
  // scan-apply: combine head prefix (aggregates) with local scan
  {
    int lane = tid & 63, w = tid >> 6;
    float m = -1e30f, n = 0.f, v = 0.f, g = 0.f;
    for (int cc = 0; cc < c; cc++) {
      size_t ix = (size_t)h * 16 + cc;
      float mb = mA[ix], nb = nA[ix], gb = gA[ix];
      float vb = vA[ix * 64 + lane];
      float mn = fmaxf(m, mb);
      float ea = expf(m - mn), eb = expf(mb - mn);
      n = n * ea + nb * eb;
      v = v * ea + vb * eb;
      m = mn; g += gb;
    }
#pragma unroll 4
    for (int i = 0; i < 16; i++) {
      int row = w * 16 + i;
      int gw = h * 1024 + c * 64 + row;
      float ml = mloc[gw], nl = nloc[gw], gl = gloc[gw];
      float vl = vloc[(size_t)gw * 64 + lane];
      float mf = fmaxf(m, ml);
      float ep = expf(m - mf), el = expf(ml - mf);
      float nf = n * ep + nl * el;
      float vf = v * ep + vl * el;
      float inv = 1.f / (nf + 1e-5f);
      lin_s[row][lane] = vf * inv;
      if (lane == 0) {
        wt_s[row] = expf(sim[gw] - mf) * inv;
        gc_s[row] = g + gl;
      }
    }
  }
  __syncthreads();
  const int t0 = (tid >> 4) * 4, n0 = (tid & 15) * 4;
  float y[4][4] = {};
  // inter-chunk: q @ S_before (S in LDS)
  for (int p = 0; p < 64; p++) {
    float av[4];
#pragma unroll
    for (int i2 = 0; i2 < 4; i2++) av[i2] = qls[t0 + i2][p];
    float4 bv = *(const float4*)&S[p * 64 + n0];
#pragma unroll
    for (int i2 = 0; i2 < 4; i2++) {
      y[i2][0] += av[i2] * bv.x; y[i2][1] += av[i2] * bv.y;
      y[i2][2] += av[i2] * bv.z; y[i2][3] += av[i2] * bv.w;
    }
  }
  // intra-chunk, two 32-wide s slabs
  const int tg = tid >> 3;
  const int s2b = (tid & 7) * 4;
  for (int s0 = 0; s0 < 64; s0 += 32) {
    float pv[2][4] = {};
    for (int k2 = 0; k2 < 64; k2++) {
      float a0 = qls[tg * 2][k2], a1 = qls[tg * 2 + 1][k2];
#pragma unroll
      for (int j = 0; j < 4; j++) {
        float b = vls[s0 + s2b + j][k2];
        pv[0][j] += a0 * b;
        pv[1][j] += a1 * b;
      }
    }
#pragma unroll
    for (int ii = 0; ii < 2; ii++)
#pragma unroll
      for (int j = 0; j < 4; j++) {
        int t = tg * 2 + ii, ss = s0 + s2b + j;
        P[t][ss - s0] = (ss <= t) ? pv[ii][j] * gzs[ss] : 0.f;
      }
    __syncthreads();
    for (int ss = 0; ss < 32; ss++) {
      float pr[4];
#pragma unroll
      for (int i2 = 0; i2 < 4; i2++) pr[i2] = P[t0 + i2][ss];
      float4 kvv = *(const float4*)&kls[s0 + ss][n0];
#pragma unroll
      for (int i2 = 0; i2 < 4; i2++) {
        y[i2][0] += pr[i2] * kvv.x; y[i2][1] += pr[i2] * kvv.y;
        y[i2][2] += pr[i2] * kvv.z; y[i2][3] += pr[i2] * kvv.w;
      }
    }
    __syncthreads();
  }
  float sc = scale[h];
#pragma unroll
  for (int i2 = 0; i2 < 4; i2++) {
    int lrow = t0 + i2;
    int l = c * 64 + lrow;
    size_t il = (size_t)h * 1024 + l;
    float gcv = gc_s[lrow], wv = wt_s[lrow], qv = qs[il];
    float den = 1.f / (gcv + 1e-5f);
    float4 lv = *(const float4*)&lin_s[lrow][n0];
    float yl0 = qv * lv.x, yl1 = qv * lv.y, yl2 = qv * lv.z, yl3 = qv * lv.w;
    float yb0 = sc * y[i2][0] * den, yb1 = sc * y[i2][1] * den;
    float yb2 = sc * y[i2][2] * den, yb3 = sc * y[i2][3] * den;
    float* dst = Yc + (size_t)l * 1024 + h * 64 + n0;
    dst[0] = yb0 + (yl0 - yb0) * wv;
    dst[1] = yb1 + (yl1 - yb1) * wv;
    dst[2] = yb2 + (yl2 - yb2) * wv;
    dst[3] = yb3 + (yl3 - yb3) * wv;
  }
}

// ---------------- row l2norm over D=1024 + cast ----------------
__global__ void rownorm_cast_k(const float* __restrict__ Y, bf16* __restrict__ out) {
  __shared__ float red[4];
  int l = blockIdx.x, tid = threadIdx.x;
  float4 v = ((const float4*)(Y + (size_t)l * 1024))[tid];
  float ss = v.x * v.x + v.y * v.y + v.z * v.z + v.w * v.w;
  ss = wave_sum(ss);
  int wid = tid >> 6, lane = tid & 63;
  if (lane == 0) red[wid] = ss;
  __syncthreads();
  float tot = red[0] + red[1] + red[2] + red[3];
  float inv = 1.f / fmaxf(sqrtf(tot), 1e-12f);
  bf16x4 o;
  o.v[0] = __float2bfloat16(v.x * inv); o.v[1] = __float2bfloat16(v.y * inv);
  o.v[2] = __float2bfloat16(v.z * inv); o.v[3] = __float2bfloat16(v.w * inv);
  ((bf16x4*)(out + (size_t)l * 1024))[tid] = o;
}

// ======================================================================
extern "C" void kernel_launch(void* const* d_in, const int* in_sizes, int n_in,
                              void* d_out, int out_size, void* d_ws, size_t ws_size,
                              hipStream_t stream) {
  (void)in_sizes; (void)n_in; (void)out_size; (void)ws_size;
  const float* x     = (const float*)d_in[0];
  const float* basis = (const float*)d_in[1];
  const float* mphiW = (const float*)d_in[2];
  const float* mphiB = (const float*)d_in[3];
  const float* wqW = (const float*)d_in[4];  const float* wqB = (const float*)d_in[5];
  const float* wkW = (const float*)d_in[6];  const float* wkB = (const float*)d_in[7];
  const float* wvW = (const float*)d_in[8];  const float* wvB = (const float*)d_in[9];
  const float* woW = (const float*)d_in[10]; const float* woB = (const float*)d_in[11];
  const float* wgW = (const float*)d_in[12]; const float* wgB = (const float*)d_in[13];
  const float* kvs = (const float*)d_in[14];
  float* out = (float*)d_out;
  char* ws = (char*)d_ws;

  bf16*  Y_T     = (bf16*)(ws + 0x0000000UL);   // [16][1024 o][1024 s] bf16 (32MB)
  bf16*  Tbuf    = (bf16*)(ws + 0x2000000UL);   // [16][1024 l][1024 s] bf16 (32MB)
  bf16*  mphi_bf = (bf16*)(ws + 0x4000000UL);   // [1024][16384] bf16 (32MB)
  float* part2a  = (float*)(ws + 0x4000000UL);  // [8][1M] f32 (aliases mphi; dead after stage-A)
  float* qkvf    = (float*)(ws + 0x4000000UL);  // [3][1M] f32 (after reduce16)
  float* part8   = (float*)(ws + 0x4000000UL);  // [4][1M] f32 (after apply_attn)
  bf16*  x_bf    = (bf16*)(ws + 0x6000000UL);   // (2MB)
  bf16*  xtil_bf = (bf16*)(ws + 0x6200000UL);   // (2MB)
  bf16*  wqkv_bf = (bf16*)(ws + 0x6400000UL);   // (6MB)
  bf16*  wo_bf   = (bf16*)(ws + 0x6A00000UL);   // (2MB)
  float* qkv_bias= (float*)(ws + 0x6C00000UL);  // (64KB)
  float* part2b  = (float*)(ws + 0x6C10000UL);  // [8][1M] f32 (32MB; dead after reduce16)
  // post-reduce16 buffers (inside the dead part2b region):
  float* kn      = (float*)(ws + 0x6C10000UL);  // [16,1024,64] (4MB)
  float* vn      = (float*)(ws + 0x7010000UL);  // (4MB)
  float* Mc      = (float*)(ws + 0x7410000UL);  // [16][16][4096] (4MB)
  float* Yc      = (float*)(ws + 0x7810000UL);  // [1024][1024] f32 (4MB)
  bf16*  ynorm   = (bf16*)(ws + 0x7C10000UL);   // (2MB)
  float* simb    = (float*)(ws + 0x7E10000UL);
  float* gzb     = (float*)(ws + 0x7E20000UL);
  float* qsb     = (float*)(ws + 0x7E30000UL);
  // scan scratch (inside dead Tbuf region, after stage-B):
  float* vloc = (float*)(ws + 0x2000000UL);  // [16,1024,64] (4MB)
  float* mloc = (float*)(ws + 0x2400000UL);
  float* nloc = (float*)(ws + 0x2410000UL);
  float* gloc = (float*)(ws + 0x2420000UL);
  float* mA   = (float*)(ws + 0x2430000UL);
  float* nA   = (float*)(ws + 0x2431000UL);
  float* gA   = (float*)(ws + 0x2432000UL);
  float* vA   = (float*)(ws + 0x2440000UL);  // [16,16,64]

  // prep: all weight/x casts + bias pack in one launch
  prep_cast_k<<<10764, 256, 0, stream>>>(mphiW, wqW, wkW, wvW, woW, x, wqB, wkB, wvB,
                                         mphi_bf, wqkv_bf, wo_bf, x_bf, qkv_bias);
  build_T_k<<<8192, 256, 0, stream>>>(basis, Tbuf);

  // stage-A: Y_T[k][o][s] = Mphi_k @ X^T  (16 batched dense GEMMs, K=1024)
  gemm_bt<0, 1, 0, 0><<<1024, 256, 0, stream>>>(
      mphi_bf, 1024L, 16384, x_bf, 0L, 1024, (void*)Y_T, (void*)Y_T, 1 << 28,
      1048576L, 1024, nullptr, 0, 1024);

  // stage-B: x_tilde = sum_k T_k @ Y_T[k]^T  (triangular, split-K x16 = one
  // panel per bz, no-dbuf 4+ blocks/CU regime; partials in two regions)
  gemm_bt<1, 0, 0, 0><<<1024, 256, 0, stream>>>(
      Tbuf, 1048576L, 1024, Y_T, 1048576L, 1024, (void*)part2a, (void*)part2b, 8,
      1048576L, 1024, nullptr, 0, 1024);
  reduce16_k<<<1024, 256, 0, stream>>>(part2a, part2b, mphiB, xtil_bf);

  // stage3: q,k,v
  gemm_bt<0, 0, 1, 1><<<192, 256, 0, stream>>>(
      xtil_bf, 0L, 1024, wqkv_bf, 1048576L, 1024, (void*)qkvf, (void*)qkvf, 1 << 28,
      1048576L, 1024, qkv_bias, 1024, 1024);

  // stage4: normalize k,v; sim; qsum; gates
  qkv_post_k<<<4096, 256, 0, stream>>>(qkvf, wgW, wgB, kvs, kn, vn, simb, gzb, qsb);

  // stage5+6a: fused local scan + gated outer product
  scan_outer_k<<<dim3(16, 16), 256, 0, stream>>>(simb, gzb, vn, kn,
                                                 vloc, mloc, nloc, gloc,
                                                 mA, nA, vA, gA, Mc);

  // stage6b: fused scan-apply + state prefix + attn + blend
  apply_attn_k<<<dim3(16, 16), 256, 0, stream>>>(qkvf, vn, kn, gzb, simb, qsb,
                                                 mloc, nloc, gloc, vloc,
                                                 mA, nA, gA, vA, Mc, kvs, Yc);

  // stage7: row l2norm + cast
  rownorm_cast_k<<<1024, 256, 0, stream>>>(Yc, ynorm);

  // stage8: out = Ynorm @ wo^T + b (split-K x4)
  gemm_bt<0, 0, 0, 1><<<256, 256, 0, stream>>>(
      ynorm, 256L, 1024, wo_bf, 256L, 1024, (void*)part8, (void*)part8, 1 << 28,
      1048576L, 1024, nullptr, 0, 256);
  reduce4f_k<<<1024, 256, 0, stream>>>(part8, woB, out);
}